// Round 1
// baseline (870.990 us; speedup 1.0000x reference)
//
#include <hip/hip_runtime.h>
#include <math.h>

// Problem constants (fixed by setup_inputs)
constexpr int Bb = 4, Hc = 64, Wc = 64, Cc = 256, Cf = 128, E = 64, KK = 25, F = 256;
constexpr int Hf = 128, Wf = 128;
constexpr int Nc = Bb * Hc * Wc;   // 16384 coarse pixels
constexpr int Nf = Bb * Hf * Wf;   // 65536 fine pixels

// ---------------------------------------------------------------------------
// K1: gate = sigmoid(coarse . gate_w + gate_b)  per coarse pixel
// one wave per pixel, float4 loads, shuffle reduce
__global__ __launch_bounds__(256) void gate_kernel(
    const float* __restrict__ coarse, const float* __restrict__ gw,
    const float* __restrict__ gb, float* __restrict__ gatec) {
  int px   = blockIdx.x * 4 + (threadIdx.x >> 6);
  int lane = threadIdx.x & 63;
  const float4 a = *(const float4*)(coarse + (size_t)px * 256 + lane * 4);
  const float4 w = *(const float4*)(gw + lane * 4);
  float v = a.x * w.x + a.y * w.y + a.z * w.z + a.w * w.w;
  #pragma unroll
  for (int off = 32; off; off >>= 1) v += __shfl_xor(v, off);
  if (lane == 0) gatec[px] = 1.f / (1.f + expf(-(v + gb[0])));
}

// ---------------------------------------------------------------------------
// K2/K3: 1x1 conv (embedding): out[px, 0..63] = in[px, 0..Kin-1] @ w + bias?
// 64px x 64ch tile per 256-thread block; K staged in 64-chunks.
__global__ __launch_bounds__(256) void emb1x1_kernel(
    const float* __restrict__ in, const float* __restrict__ w,
    const float* __restrict__ bias, float* __restrict__ out, int Kin) {
  __shared__ float a_s[64 * 68];   // [px][64k] pad 68
  __shared__ float w_s[64 * 64];   // [k][c]
  int t = threadIdx.x;
  int pxb = blockIdx.x * 64;
  int tm = t >> 4, tn = t & 15;    // 16 row-groups x 16 col-groups
  float acc[4][4] = {{0.f}};

  for (int kt = 0; kt < Kin; kt += 64) {
    for (int idx = t; idx < 64 * 64; idx += 256) {
      int px = idx >> 6, k = idx & 63;
      a_s[px * 68 + k] = in[(size_t)(pxb + px) * Kin + kt + k];
    }
    for (int idx = t; idx < 64 * 64; idx += 256) {
      int k = idx >> 6, c = idx & 63;
      w_s[idx] = w[(size_t)(kt + k) * 64 + c];
    }
    __syncthreads();
    for (int kk = 0; kk < 64; kk += 4) {
      float4 a4[4];
      #pragma unroll
      for (int mi = 0; mi < 4; mi++)
        a4[mi] = *(const float4*)&a_s[(tm * 4 + mi) * 68 + kk];
      #pragma unroll
      for (int kx = 0; kx < 4; kx++) {
        #pragma unroll
        for (int ni = 0; ni < 4; ni++) {
          float wv = w_s[(kk + kx) * 64 + tn + 16 * ni];
          const float* ap0 = (const float*)&a4[0];
          const float* ap1 = (const float*)&a4[1];
          const float* ap2 = (const float*)&a4[2];
          const float* ap3 = (const float*)&a4[3];
          acc[0][ni] += ap0[kx] * wv;
          acc[1][ni] += ap1[kx] * wv;
          acc[2][ni] += ap2[kx] * wv;
          acc[3][ni] += ap3[kx] * wv;
        }
      }
    }
    __syncthreads();
  }
  #pragma unroll
  for (int mi = 0; mi < 4; mi++) {
    size_t gpx = (size_t)pxb + tm * 4 + mi;
    #pragma unroll
    for (int ni = 0; ni < 4; ni++) {
      int c = tn + 16 * ni;
      float bv = bias ? bias[c] : 0.f;
      out[gpx * 64 + c] = acc[mi][ni] + bv;
    }
  }
}

// ---------------------------------------------------------------------------
// K4/K5: 3x3 content conv, 64 -> 25 channels, SAME zero-pad.
// 8x8 pixel tile + halo in LDS; weights via wave-uniform scalar loads.
template <int NM>
__device__ inline void conv_accum(const float* a_s, const float* __restrict__ wg,
                                  int cgrp, int pi, int pj, float* acc) {
  #pragma unroll
  for (int di = 0; di < 3; di++) {
    #pragma unroll
    for (int dj = 0; dj < 3; dj++) {
      const float* wp = wg + (size_t)((di * 3 + dj) * 64) * 25 + cgrp;
      const float* ap = a_s + ((pi + di) * 10 + (pj + dj)) * 65;
      #pragma unroll 4
      for (int k = 0; k < 64; k++) {
        float a = ap[k];
        #pragma unroll
        for (int m = 0; m < NM; m++) acc[m] += a * wp[k * 25 + 4 * m];
      }
    }
  }
}

__global__ __launch_bounds__(256) void content_kernel(
    const float* __restrict__ in, const float* __restrict__ wg,
    const float* __restrict__ cb, float* __restrict__ out, int Hd, int Wd) {
  __shared__ float a_s[100 * 65];
  int t = threadIdx.x;
  int b = blockIdx.z;
  int i0 = blockIdx.y * 8, j0 = blockIdx.x * 8;
  for (int idx = t; idx < 100 * 64; idx += 256) {
    int cell = idx >> 6, k = idx & 63;
    int gi = i0 - 1 + cell / 10;
    int gj = j0 - 1 + cell % 10;
    float v = 0.f;
    if (gi >= 0 && gi < Hd && gj >= 0 && gj < Wd)
      v = in[(size_t)((b * Hd + gi) * Wd + gj) * 64 + k];
    a_s[cell * 65 + k] = v;
  }
  __syncthreads();
  int px = t & 63;
  int cgrp = __builtin_amdgcn_readfirstlane(t >> 6);  // wave-uniform -> s_loads for weights
  int pi = px >> 3, pj = px & 7;
  float acc[7] = {0.f, 0.f, 0.f, 0.f, 0.f, 0.f, 0.f};
  if (cgrp == 0) conv_accum<7>(a_s, wg, cgrp, pi, pj, acc);
  else           conv_accum<6>(a_s, wg, cgrp, pi, pj, acc);
  int NM = (cgrp == 0) ? 7 : 6;
  int gi = i0 + pi, gj = j0 + pj;
  size_t base = (size_t)((b * Hd + gi) * Wd + gj) * 25;
  for (int m = 0; m < NM; m++) {
    int ch = cgrp + 4 * m;
    out[base + ch] = acc[m] + cb[ch];
  }
}

// ---------------------------------------------------------------------------
// K6: fused softmax + CARAFE + proj1(256x256) + proj2(256x256) + gated mix.
// 32 fine pixels (8w x 4h) per 256-thread block. cu / c_out live in LDS only.
__global__ __launch_bounds__(256) void fuse_kernel(
    const float* __restrict__ coarse, const float* __restrict__ kff,
    const float* __restrict__ kfc, const float* __restrict__ gatec,
    const float* __restrict__ W1, const float* __restrict__ b1,
    const float* __restrict__ W2, const float* __restrict__ b2,
    float* __restrict__ out) {
  __shared__ float m_s[32][28];      // softmax masks
  __shared__ float g_s[32];          // gate per fine px
  __shared__ float cu_s[32 * 260];   // cu, then c_out (reused)
  __shared__ float wt_s[256 * 20];   // W k-tile, transposed [c][16k + 4 pad]
  int t = threadIdx.x;
  int b = blockIdx.z;
  int i0 = blockIdx.y * 4, j0 = blockIdx.x * 8;

  // P0: masks (softmax of kff + upsampled kfc) + gate
  if (t < 32) {
    int ti = t >> 3, tj = t & 7;
    int i = i0 + ti, j = j0 + tj;
    size_t fpx = (size_t)((b * 128 + i) * 128 + j);
    size_t cpx = (size_t)((b * 64 + (i >> 1)) * 64 + (j >> 1));
    float v[25];
    float mx = -1e30f;
    #pragma unroll
    for (int m = 0; m < 25; m++) {
      v[m] = kff[fpx * 25 + m] + kfc[cpx * 25 + m];
      mx = fmaxf(mx, v[m]);
    }
    float s = 0.f;
    #pragma unroll
    for (int m = 0; m < 25; m++) { v[m] = expf(v[m] - mx); s += v[m]; }
    float inv = 1.f / s;
    #pragma unroll
    for (int m = 0; m < 25; m++) m_s[t][m] = v[m] * inv;
    g_s[t] = gatec[cpx];
  }
  __syncthreads();

  // P1: carafe -> cu_s ; thread t owns channel c = t
  {
    int c = t;
    for (int px = 0; px < 32; px++) {
      int ti = px >> 3, tj = px & 7;
      int hc = ((i0 + ti) >> 1) - 2, wc = ((j0 + tj) >> 1) - 2;
      float acc = 0.f;
      #pragma unroll
      for (int di = 0; di < 5; di++) {
        int h = hc + di;
        if (h < 0 || h >= 64) continue;
        const float* crow = coarse + (size_t)(b * 64 + h) * 64 * 256;
        #pragma unroll
        for (int dj = 0; dj < 5; dj++) {
          int w = wc + dj;
          if (w < 0 || w >= 64) continue;
          acc += m_s[px][di * 5 + dj] * crow[(size_t)w * 256 + c];
        }
      }
      cu_s[px * 260 + c] = acc;
    }
  }
  __syncthreads();

  float acc[4][8];
  int tm = t >> 5, tn = t & 31;

  // ---- GEMM1: c_out = cu @ W1 + b1 ----
  #pragma unroll
  for (int mi = 0; mi < 4; mi++)
    #pragma unroll
    for (int ni = 0; ni < 8; ni++) acc[mi][ni] = 0.f;
  for (int kt = 0; kt < 256; kt += 16) {
    for (int rep = 0; rep < 16; rep++)
      wt_s[t * 20 + rep] = W1[(size_t)(kt + rep) * 256 + t];
    __syncthreads();
    #pragma unroll
    for (int kk = 0; kk < 16; kk += 4) {
      float4 a4[4];
      #pragma unroll
      for (int mi = 0; mi < 4; mi++)
        a4[mi] = *(const float4*)&cu_s[(tm * 4 + mi) * 260 + kt + kk];
      #pragma unroll
      for (int ni = 0; ni < 8; ni++) {
        float4 w4 = *(const float4*)&wt_s[(tn + 32 * ni) * 20 + kk];
        #pragma unroll
        for (int mi = 0; mi < 4; mi++) {
          acc[mi][ni] += a4[mi].x * w4.x + a4[mi].y * w4.y +
                         a4[mi].z * w4.z + a4[mi].w * w4.w;
        }
      }
    }
    __syncthreads();
  }
  // bias, write c_out into cu_s
  #pragma unroll
  for (int ni = 0; ni < 8; ni++) {
    float bv = b1[tn + 32 * ni];
    #pragma unroll
    for (int mi = 0; mi < 4; mi++) acc[mi][ni] += bv;
  }
  __syncthreads();  // ensure all GEMM1 reads of cu_s are done (redundant but safe)
  #pragma unroll
  for (int mi = 0; mi < 4; mi++)
    #pragma unroll
    for (int ni = 0; ni < 8; ni++)
      cu_s[(tm * 4 + mi) * 260 + tn + 32 * ni] = acc[mi][ni];
  __syncthreads();

  // ---- GEMM2: f_out = c_out @ W2 + b2 ----
  #pragma unroll
  for (int mi = 0; mi < 4; mi++)
    #pragma unroll
    for (int ni = 0; ni < 8; ni++) acc[mi][ni] = 0.f;
  for (int kt = 0; kt < 256; kt += 16) {
    for (int rep = 0; rep < 16; rep++)
      wt_s[t * 20 + rep] = W2[(size_t)(kt + rep) * 256 + t];
    __syncthreads();
    #pragma unroll
    for (int kk = 0; kk < 16; kk += 4) {
      float4 a4[4];
      #pragma unroll
      for (int mi = 0; mi < 4; mi++)
        a4[mi] = *(const float4*)&cu_s[(tm * 4 + mi) * 260 + kt + kk];
      #pragma unroll
      for (int ni = 0; ni < 8; ni++) {
        float4 w4 = *(const float4*)&wt_s[(tn + 32 * ni) * 20 + kk];
        #pragma unroll
        for (int mi = 0; mi < 4; mi++) {
          acc[mi][ni] += a4[mi].x * w4.x + a4[mi].y * w4.y +
                         a4[mi].z * w4.z + a4[mi].w * w4.w;
        }
      }
    }
    __syncthreads();
  }

  // ---- mix + store ----
  #pragma unroll
  for (int mi = 0; mi < 4; mi++) {
    int r = tm * 4 + mi;
    int i = i0 + (r >> 3), j = j0 + (r & 7);
    float g = g_s[r];
    size_t obase = (size_t)((b * 128 + i) * 128 + j) * 256;
    #pragma unroll
    for (int ni = 0; ni < 8; ni++) {
      int c = tn + 32 * ni;
      float f_out = acc[mi][ni] + b2[c];
      float c_out = cu_s[r * 260 + c];
      out[obase + c] = g * f_out + (1.f - g) * c_out;
    }
  }
}

// ---------------------------------------------------------------------------
extern "C" void kernel_launch(void* const* d_in, const int* in_sizes, int n_in,
                              void* d_out, int out_size, void* d_ws, size_t ws_size,
                              hipStream_t stream) {
  const float* fine        = (const float*)d_in[0];
  const float* coarse      = (const float*)d_in[1];
  const float* gate_w      = (const float*)d_in[2];
  const float* gate_b      = (const float*)d_in[3];
  const float* ss_fine_w   = (const float*)d_in[4];
  const float* ss_fine_b   = (const float*)d_in[5];
  const float* ss_coarse_w = (const float*)d_in[6];
  const float* ss_content_w= (const float*)d_in[7];
  const float* ss_content_b= (const float*)d_in[8];
  const float* W1          = (const float*)d_in[9];   // coarse_proj_w
  const float* b1          = (const float*)d_in[10];
  const float* W2          = (const float*)d_in[11];  // fine_proj_w
  const float* b2          = (const float*)d_in[12];
  float* out = (float*)d_out;

  char* ws = (char*)d_ws;
  float* gatec = (float*)(ws);                               // Nc floats (64 KB)
  float* femb  = (float*)(ws + (size_t)131072);              // Nf*64 (16 MB)
  float* cemb  = (float*)(ws + (size_t)131072 + (size_t)Nf * 64 * 4);           // Nc*64 (4 MB)
  float* kff   = (float*)(ws + (size_t)131072 + (size_t)Nf * 64 * 4 + (size_t)Nc * 64 * 4);  // Nf*25
  float* kfc   = (float*)(ws + (size_t)131072 + (size_t)Nf * 64 * 4 + (size_t)Nc * 64 * 4
                             + (size_t)Nf * 25 * 4);         // Nc*25

  gate_kernel<<<Nc / 4, 256, 0, stream>>>(coarse, gate_w, gate_b, gatec);
  emb1x1_kernel<<<Nf / 64, 256, 0, stream>>>(fine, ss_fine_w, ss_fine_b, femb, 128);
  emb1x1_kernel<<<Nc / 64, 256, 0, stream>>>(coarse, ss_coarse_w, nullptr, cemb, 256);
  content_kernel<<<dim3(Wf / 8, Hf / 8, Bb), 256, 0, stream>>>(femb, ss_content_w, ss_content_b, kff, Hf, Wf);
  content_kernel<<<dim3(Wc / 8, Hc / 8, Bb), 256, 0, stream>>>(cemb, ss_content_w, ss_content_b, kfc, Hc, Wc);
  fuse_kernel<<<dim3(Wf / 8, Hf / 4, Bb), 256, 0, stream>>>(coarse, kff, kfc, gatec, W1, b1, W2, b2, out);
}

// Round 2
// 294.674 us; speedup vs baseline: 2.9558x; 2.9558x over previous
//
#include <hip/hip_runtime.h>
#include <math.h>

// Problem constants (fixed by setup_inputs)
constexpr int Bb = 4, Hc = 64, Wc = 64, Cc = 256, Cf = 128, E = 64, KK = 25, F = 256;
constexpr int Hf = 128, Wf = 128;
constexpr int Nc = Bb * Hc * Wc;   // 16384 coarse pixels
constexpr int Nf = Bb * Hf * Wf;   // 65536 fine pixels

typedef __attribute__((ext_vector_type(8))) short bf16x8;
typedef __attribute__((ext_vector_type(4))) float f32x4;

__device__ inline unsigned short f2b(float f) {
  union { float f; unsigned u; } v; v.f = f;
  return (unsigned short)((v.u + 0x7FFF + ((v.u >> 16) & 1)) >> 16);
}

// ---------------------------------------------------------------------------
// K0: transpose + bf16-convert the two 256x256 projection weights: Wt[n][k]
__global__ __launch_bounds__(256) void wprep_kernel(
    const float* __restrict__ W1, const float* __restrict__ W2,
    unsigned short* __restrict__ Wt1, unsigned short* __restrict__ Wt2) {
  __shared__ float tile[64][65];
  const float* W = blockIdx.z ? W2 : W1;
  unsigned short* Wt = blockIdx.z ? Wt2 : Wt1;
  int k0 = blockIdx.x * 64, n0 = blockIdx.y * 64;
  int r0 = threadIdx.x >> 6, c = threadIdx.x & 63;
  for (int r = r0; r < 64; r += 4)
    tile[r][c] = W[(size_t)(k0 + r) * 256 + n0 + c];
  __syncthreads();
  for (int r = r0; r < 64; r += 4)
    Wt[(size_t)(n0 + r) * 256 + k0 + c] = f2b(tile[c][r]);
}

// ---------------------------------------------------------------------------
// K1: gate = sigmoid(coarse . gate_w + gate_b)  per coarse pixel
__global__ __launch_bounds__(256) void gate_kernel(
    const float* __restrict__ coarse, const float* __restrict__ gw,
    const float* __restrict__ gb, float* __restrict__ gatec) {
  int px   = blockIdx.x * 4 + (threadIdx.x >> 6);
  int lane = threadIdx.x & 63;
  const float4 a = *(const float4*)(coarse + (size_t)px * 256 + lane * 4);
  const float4 w = *(const float4*)(gw + lane * 4);
  float v = a.x * w.x + a.y * w.y + a.z * w.z + a.w * w.w;
  #pragma unroll
  for (int off = 32; off; off >>= 1) v += __shfl_xor(v, off);
  if (lane == 0) gatec[px] = 1.f / (1.f + expf(-(v + gb[0])));
}

// ---------------------------------------------------------------------------
// K2/K3: 1x1 conv (embedding): out[px, 0..63] = in[px, 0..Kin-1] @ w + bias?
__global__ __launch_bounds__(256) void emb1x1_kernel(
    const float* __restrict__ in, const float* __restrict__ w,
    const float* __restrict__ bias, float* __restrict__ out, int Kin) {
  __shared__ float a_s[64 * 68];
  __shared__ float w_s[64 * 64];
  int t = threadIdx.x;
  int pxb = blockIdx.x * 64;
  int tm = t >> 4, tn = t & 15;
  float acc[4][4] = {{0.f}};

  for (int kt = 0; kt < Kin; kt += 64) {
    for (int idx = t; idx < 64 * 64; idx += 256) {
      int px = idx >> 6, k = idx & 63;
      a_s[px * 68 + k] = in[(size_t)(pxb + px) * Kin + kt + k];
    }
    for (int idx = t; idx < 64 * 64; idx += 256) {
      int k = idx >> 6, c = idx & 63;
      w_s[idx] = w[(size_t)(kt + k) * 64 + c];
    }
    __syncthreads();
    for (int kk = 0; kk < 64; kk += 4) {
      float4 a4[4];
      #pragma unroll
      for (int mi = 0; mi < 4; mi++)
        a4[mi] = *(const float4*)&a_s[(tm * 4 + mi) * 68 + kk];
      #pragma unroll
      for (int kx = 0; kx < 4; kx++) {
        #pragma unroll
        for (int ni = 0; ni < 4; ni++) {
          float wv = w_s[(kk + kx) * 64 + tn + 16 * ni];
          const float* ap0 = (const float*)&a4[0];
          const float* ap1 = (const float*)&a4[1];
          const float* ap2 = (const float*)&a4[2];
          const float* ap3 = (const float*)&a4[3];
          acc[0][ni] += ap0[kx] * wv;
          acc[1][ni] += ap1[kx] * wv;
          acc[2][ni] += ap2[kx] * wv;
          acc[3][ni] += ap3[kx] * wv;
        }
      }
    }
    __syncthreads();
  }
  #pragma unroll
  for (int mi = 0; mi < 4; mi++) {
    size_t gpx = (size_t)pxb + tm * 4 + mi;
    #pragma unroll
    for (int ni = 0; ni < 4; ni++) {
      int c = tn + 16 * ni;
      float bv = bias ? bias[c] : 0.f;
      out[gpx * 64 + c] = acc[mi][ni] + bv;
    }
  }
}

// ---------------------------------------------------------------------------
// K4/K5: 3x3 content conv, 64 -> 25 channels, SAME zero-pad.
template <int NM>
__device__ inline void conv_accum(const float* a_s, const float* __restrict__ wg,
                                  int cgrp, int pi, int pj, float* acc) {
  #pragma unroll
  for (int di = 0; di < 3; di++) {
    #pragma unroll
    for (int dj = 0; dj < 3; dj++) {
      const float* wp = wg + (size_t)((di * 3 + dj) * 64) * 25 + cgrp;
      const float* ap = a_s + ((pi + di) * 10 + (pj + dj)) * 65;
      #pragma unroll 4
      for (int k = 0; k < 64; k++) {
        float a = ap[k];
        #pragma unroll
        for (int m = 0; m < NM; m++) acc[m] += a * wp[k * 25 + 4 * m];
      }
    }
  }
}

__global__ __launch_bounds__(256) void content_kernel(
    const float* __restrict__ in, const float* __restrict__ wg,
    const float* __restrict__ cb, float* __restrict__ out, int Hd, int Wd) {
  __shared__ float a_s[100 * 65];
  int t = threadIdx.x;
  int b = blockIdx.z;
  int i0 = blockIdx.y * 8, j0 = blockIdx.x * 8;
  for (int idx = t; idx < 100 * 64; idx += 256) {
    int cell = idx >> 6, k = idx & 63;
    int gi = i0 - 1 + cell / 10;
    int gj = j0 - 1 + cell % 10;
    float v = 0.f;
    if (gi >= 0 && gi < Hd && gj >= 0 && gj < Wd)
      v = in[(size_t)((b * Hd + gi) * Wd + gj) * 64 + k];
    a_s[cell * 65 + k] = v;
  }
  __syncthreads();
  int px = t & 63;
  int cgrp = __builtin_amdgcn_readfirstlane(t >> 6);
  int pi = px >> 3, pj = px & 7;
  float acc[7] = {0.f, 0.f, 0.f, 0.f, 0.f, 0.f, 0.f};
  if (cgrp == 0) conv_accum<7>(a_s, wg, cgrp, pi, pj, acc);
  else           conv_accum<6>(a_s, wg, cgrp, pi, pj, acc);
  int NM = (cgrp == 0) ? 7 : 6;
  int gi = i0 + pi, gj = j0 + pj;
  size_t base = (size_t)((b * Hd + gi) * Wd + gj) * 25;
  for (int m = 0; m < NM; m++) {
    int ch = cgrp + 4 * m;
    out[base + ch] = acc[m] + cb[ch];
  }
}

// ---------------------------------------------------------------------------
// K6: fused softmax + CARAFE(MFMA) + proj1(MFMA) + proj2(MFMA) + gated mix.
// Block = 256 threads = 4 waves; 32 fine px (4h x 8w); N=256 split 64ch/wave.
// LDS: win_t[256][72] bf16 (overlaid later by cu_s[32][264] bf16), m_ext, g_s.
__global__ __launch_bounds__(256) void fuse_mfma_kernel(
    const float* __restrict__ coarse, const float* __restrict__ kff,
    const float* __restrict__ kfc, const float* __restrict__ gatec,
    const unsigned short* __restrict__ Wt1, const float* __restrict__ b1,
    const unsigned short* __restrict__ Wt2, const float* __restrict__ b2,
    float* __restrict__ out) {
  __shared__ __align__(16) unsigned short buf[256 * 72];   // 36864 B
  __shared__ __align__(16) unsigned short m_ext[32 * 72];  // 4608 B
  __shared__ float g_s[32];
  unsigned short* win_t = buf;   // [ch 0..255][tap 0..63(+pad)]
  unsigned short* cu_s  = buf;   // later: [px 0..31][ch, stride 264]

  int t = threadIdx.x;
  int b = blockIdx.z;
  int i0 = blockIdx.y * 4, j0 = blockIdx.x * 8;
  int hw0 = (i0 >> 1) - 2, ww0 = (j0 >> 1) - 2;

  // ---- phase A: stage 6x8 coarse window (thread t = channel t), masks ----
  {
    #pragma unroll
    for (int p0 = 0; p0 < 48; p0 += 4) {
      unsigned short vals[4];
      #pragma unroll
      for (int q = 0; q < 4; q++) {
        int p = p0 + q;
        int h = hw0 + (p >> 3), w = ww0 + (p & 7);
        float v = 0.f;
        if (h >= 0 && h < 64 && w >= 0 && w < 64)
          v = coarse[(size_t)((b * 64 + h) * 64 + w) * 256 + t];
        vals[q] = f2b(v);
      }
      *(short4*)&win_t[t * 72 + p0] =
          make_short4((short)vals[0], (short)vals[1], (short)vals[2], (short)vals[3]);
    }
    short4 z4 = make_short4(0, 0, 0, 0);
    *(short4*)&win_t[t * 72 + 48] = z4;
    *(short4*)&win_t[t * 72 + 52] = z4;
    *(short4*)&win_t[t * 72 + 56] = z4;
    *(short4*)&win_t[t * 72 + 60] = z4;
  }
  if (t < 32) {
    int i = i0 + (t >> 3), j = j0 + (t & 7);
    size_t fpx = (size_t)((b * 128 + i) * 128 + j);
    size_t cpx = (size_t)((b * 64 + (i >> 1)) * 64 + (j >> 1));
    float v[25];
    float mx = -1e30f;
    #pragma unroll
    for (int m = 0; m < 25; m++) {
      v[m] = kff[fpx * 25 + m] + kfc[cpx * 25 + m];
      mx = fmaxf(mx, v[m]);
    }
    float s = 0.f;
    #pragma unroll
    for (int m = 0; m < 25; m++) { v[m] = expf(v[m] - mx); s += v[m]; }
    float inv = 1.f / s;
    // zero own row, then scatter 25 mask values into window-tap positions
    unsigned* row32 = (unsigned*)&m_ext[t * 72];
    #pragma unroll
    for (int q = 0; q < 36; q++) row32[q] = 0;
    int wib = (t >> 3) >> 1, wjb = (t & 7) >> 1;
    #pragma unroll
    for (int di = 0; di < 5; di++)
      #pragma unroll
      for (int dj = 0; dj < 5; dj++)
        m_ext[t * 72 + (wib + di) * 8 + (wjb + dj)] = f2b(v[di * 5 + dj] * inv);
    g_s[t] = gatec[cpx];
  }
  __syncthreads();

  int wid = t >> 6, lane = t & 63;
  int lr = lane & 15, lg = lane >> 4;
  const f32x4 zero4 = {0.f, 0.f, 0.f, 0.f};

  // ---- GEMM0: cu[32x256] = M_ext[32x64] @ win[64x256] ----
  f32x4 acc0[2][4];
  #pragma unroll
  for (int mi = 0; mi < 2; mi++)
    #pragma unroll
    for (int ni = 0; ni < 4; ni++) acc0[mi][ni] = zero4;
  #pragma unroll
  for (int kt = 0; kt < 2; kt++) {
    bf16x8 a0 = *(const bf16x8*)&m_ext[lr * 72 + kt * 32 + lg * 8];
    bf16x8 a1 = *(const bf16x8*)&m_ext[(16 + lr) * 72 + kt * 32 + lg * 8];
    #pragma unroll
    for (int ni = 0; ni < 4; ni++) {
      bf16x8 bb = *(const bf16x8*)&win_t[(size_t)(wid * 64 + ni * 16 + lr) * 72 + kt * 32 + lg * 8];
      acc0[0][ni] = __builtin_amdgcn_mfma_f32_16x16x32_bf16(a0, bb, acc0[0][ni], 0, 0, 0);
      acc0[1][ni] = __builtin_amdgcn_mfma_f32_16x16x32_bf16(a1, bb, acc0[1][ni], 0, 0, 0);
    }
  }
  __syncthreads();  // all win_t reads done; buf becomes cu_s

  #pragma unroll
  for (int mi = 0; mi < 2; mi++)
    #pragma unroll
    for (int ni = 0; ni < 4; ni++)
      #pragma unroll
      for (int r = 0; r < 4; r++)
        cu_s[(mi * 16 + lg * 4 + r) * 264 + wid * 64 + ni * 16 + lr] = f2b(acc0[mi][ni][r]);
  __syncthreads();

  // ---- GEMM1: c_out = cu @ W1 + b1 (A from LDS, B from global bf16 Wt1) ----
  f32x4 acc1[2][4];
  #pragma unroll
  for (int mi = 0; mi < 2; mi++)
    #pragma unroll
    for (int ni = 0; ni < 4; ni++) acc1[mi][ni] = zero4;
  #pragma unroll 2
  for (int kt = 0; kt < 8; kt++) {
    bf16x8 a0 = *(const bf16x8*)&cu_s[lr * 264 + kt * 32 + lg * 8];
    bf16x8 a1 = *(const bf16x8*)&cu_s[(16 + lr) * 264 + kt * 32 + lg * 8];
    #pragma unroll
    for (int ni = 0; ni < 4; ni++) {
      bf16x8 bb = *(const bf16x8*)&Wt1[(size_t)(wid * 64 + ni * 16 + lr) * 256 + kt * 32 + lg * 8];
      acc1[0][ni] = __builtin_amdgcn_mfma_f32_16x16x32_bf16(a0, bb, acc1[0][ni], 0, 0, 0);
      acc1[1][ni] = __builtin_amdgcn_mfma_f32_16x16x32_bf16(a1, bb, acc1[1][ni], 0, 0, 0);
    }
  }
  float b1v[4];
  #pragma unroll
  for (int ni = 0; ni < 4; ni++) b1v[ni] = b1[wid * 64 + ni * 16 + lr];
  __syncthreads();  // all cu_s reads done

  #pragma unroll
  for (int mi = 0; mi < 2; mi++)
    #pragma unroll
    for (int ni = 0; ni < 4; ni++)
      #pragma unroll
      for (int r = 0; r < 4; r++)
        cu_s[(mi * 16 + lg * 4 + r) * 264 + wid * 64 + ni * 16 + lr] =
            f2b(acc1[mi][ni][r] + b1v[ni]);
  __syncthreads();

  // ---- GEMM2: f_out = c_out @ W2 + b2 ----
  f32x4 acc2[2][4];
  #pragma unroll
  for (int mi = 0; mi < 2; mi++)
    #pragma unroll
    for (int ni = 0; ni < 4; ni++) acc2[mi][ni] = zero4;
  #pragma unroll 2
  for (int kt = 0; kt < 8; kt++) {
    bf16x8 a0 = *(const bf16x8*)&cu_s[lr * 264 + kt * 32 + lg * 8];
    bf16x8 a1 = *(const bf16x8*)&cu_s[(16 + lr) * 264 + kt * 32 + lg * 8];
    #pragma unroll
    for (int ni = 0; ni < 4; ni++) {
      bf16x8 bb = *(const bf16x8*)&Wt2[(size_t)(wid * 64 + ni * 16 + lr) * 256 + kt * 32 + lg * 8];
      acc2[0][ni] = __builtin_amdgcn_mfma_f32_16x16x32_bf16(a0, bb, acc2[0][ni], 0, 0, 0);
      acc2[1][ni] = __builtin_amdgcn_mfma_f32_16x16x32_bf16(a1, bb, acc2[1][ni], 0, 0, 0);
    }
  }
  float b2v[4];
  #pragma unroll
  for (int ni = 0; ni < 4; ni++) b2v[ni] = b2[wid * 64 + ni * 16 + lr];

  // ---- mix + store: out = g*f_out + (1-g)*c_out ----
  #pragma unroll
  for (int mi = 0; mi < 2; mi++)
    #pragma unroll
    for (int ni = 0; ni < 4; ni++)
      #pragma unroll
      for (int r = 0; r < 4; r++) {
        int px = mi * 16 + lg * 4 + r;
        float g = g_s[px];
        int i = i0 + (px >> 3), j = j0 + (px & 7);
        float c_out = acc1[mi][ni][r] + b1v[ni];
        float f_out = acc2[mi][ni][r] + b2v[ni];
        out[(size_t)((b * 128 + i) * 128 + j) * 256 + wid * 64 + ni * 16 + lr] =
            g * f_out + (1.f - g) * c_out;
      }
}

// ---------------------------------------------------------------------------
extern "C" void kernel_launch(void* const* d_in, const int* in_sizes, int n_in,
                              void* d_out, int out_size, void* d_ws, size_t ws_size,
                              hipStream_t stream) {
  const float* fine        = (const float*)d_in[0];
  const float* coarse      = (const float*)d_in[1];
  const float* gate_w      = (const float*)d_in[2];
  const float* gate_b      = (const float*)d_in[3];
  const float* ss_fine_w   = (const float*)d_in[4];
  const float* ss_fine_b   = (const float*)d_in[5];
  const float* ss_coarse_w = (const float*)d_in[6];
  const float* ss_content_w= (const float*)d_in[7];
  const float* ss_content_b= (const float*)d_in[8];
  const float* W1          = (const float*)d_in[9];
  const float* b1          = (const float*)d_in[10];
  const float* W2          = (const float*)d_in[11];
  const float* b2          = (const float*)d_in[12];
  float* out = (float*)d_out;

  char* ws = (char*)d_ws;
  size_t off = 0;
  float* gatec = (float*)(ws + off); off += 131072;
  float* femb  = (float*)(ws + off); off += (size_t)Nf * 64 * 4;
  float* cemb  = (float*)(ws + off); off += (size_t)Nc * 64 * 4;
  float* kff   = (float*)(ws + off); off += (size_t)Nf * 25 * 4;
  float* kfc   = (float*)(ws + off); off += (size_t)Nc * 25 * 4;
  unsigned short* Wt1 = (unsigned short*)(ws + off); off += 65536 * 2;
  unsigned short* Wt2 = (unsigned short*)(ws + off); off += 65536 * 2;

  wprep_kernel<<<dim3(4, 4, 2), 256, 0, stream>>>(W1, W2, Wt1, Wt2);
  gate_kernel<<<Nc / 4, 256, 0, stream>>>(coarse, gate_w, gate_b, gatec);
  emb1x1_kernel<<<Nf / 64, 256, 0, stream>>>(fine, ss_fine_w, ss_fine_b, femb, 128);
  emb1x1_kernel<<<Nc / 64, 256, 0, stream>>>(coarse, ss_coarse_w, nullptr, cemb, 256);
  content_kernel<<<dim3(Wf / 8, Hf / 8, Bb), 256, 0, stream>>>(femb, ss_content_w, ss_content_b, kff, Hf, Wf);
  content_kernel<<<dim3(Wc / 8, Hc / 8, Bb), 256, 0, stream>>>(cemb, ss_content_w, ss_content_b, kfc, Hc, Wc);
  fuse_mfma_kernel<<<dim3(Wf / 8, Hf / 4, Bb), 256, 0, stream>>>(
      coarse, kff, kfc, gatec, Wt1, b1, Wt2, b2, out);
}

// Round 3
// 184.081 us; speedup vs baseline: 4.7316x; 1.6008x over previous
//
#include <hip/hip_runtime.h>
#include <math.h>

// Problem constants (fixed by setup_inputs)
constexpr int Bb = 4, Hc = 64, Wc = 64, Cc = 256, Cf = 128, E = 64, KK = 25, F = 256;
constexpr int Hf = 128, Wf = 128;
constexpr int Nc = Bb * Hc * Wc;   // 16384 coarse pixels
constexpr int Nf = Bb * Hf * Wf;   // 65536 fine pixels

typedef __attribute__((ext_vector_type(8))) short bf16x8;
typedef __attribute__((ext_vector_type(4))) float f32x4;

__device__ inline unsigned short f2b(float f) {
  union { float f; unsigned u; } v; v.f = f;
  return (unsigned short)((v.u + 0x7FFF + ((v.u >> 16) & 1)) >> 16);
}

// ---------------------------------------------------------------------------
// K0a: transpose + bf16-convert the two 256x256 projection weights: Wt[n][k]
__global__ __launch_bounds__(256) void wprep_kernel(
    const float* __restrict__ W1, const float* __restrict__ W2,
    unsigned short* __restrict__ Wt1, unsigned short* __restrict__ Wt2) {
  __shared__ float tile[64][65];
  const float* W = blockIdx.z ? W2 : W1;
  unsigned short* Wt = blockIdx.z ? Wt2 : Wt1;
  int k0 = blockIdx.x * 64, n0 = blockIdx.y * 64;
  int r0 = threadIdx.x >> 6, c = threadIdx.x & 63;
  for (int r = r0; r < 64; r += 4)
    tile[r][c] = W[(size_t)(k0 + r) * 256 + n0 + c];
  __syncthreads();
  for (int r = r0; r < 64; r += 4)
    Wt[(size_t)(n0 + r) * 256 + k0 + c] = f2b(tile[c][r]);
}

// K0b: transpose + bf16-convert small weights (emb fine/coarse, content)
__global__ __launch_bounds__(256) void sprep_kernel(
    const float* __restrict__ fw, const float* __restrict__ cw,
    const float* __restrict__ cntw, unsigned short* __restrict__ Wtf,
    unsigned short* __restrict__ Wtc, unsigned short* __restrict__ Wtcnt) {
  int t = threadIdx.x, sec = blockIdx.x;
  if (sec == 0) {
    for (int idx = t; idx < 64 * 128; idx += 256) {
      int n = idx & 63, k = idx >> 6;
      Wtf[n * 128 + k] = f2b(fw[k * 64 + n]);
    }
  } else if (sec == 1) {
    for (int idx = t; idx < 64 * 256; idx += 256) {
      int n = idx & 63, k = idx >> 6;
      Wtc[n * 256 + k] = f2b(cw[k * 64 + n]);
    }
  } else {
    // content w: (3,3,64,25) -> Wtcnt[ch(32, pad0)][tap*64+k]
    for (int idx = t; idx < 32 * 576; idx += 256) {
      int n = idx & 31, kk = idx >> 5;
      Wtcnt[n * 576 + kk] = (n < 25) ? f2b(cntw[kk * 25 + n]) : (unsigned short)0;
    }
  }
}

// ---------------------------------------------------------------------------
// K1: gate = sigmoid(coarse . gate_w + gate_b)  per coarse pixel
__global__ __launch_bounds__(256) void gate_kernel(
    const float* __restrict__ coarse, const float* __restrict__ gw,
    const float* __restrict__ gb, float* __restrict__ gatec) {
  int px   = blockIdx.x * 4 + (threadIdx.x >> 6);
  int lane = threadIdx.x & 63;
  const float4 a = *(const float4*)(coarse + (size_t)px * 256 + lane * 4);
  const float4 w = *(const float4*)(gw + lane * 4);
  float v = a.x * w.x + a.y * w.y + a.z * w.z + a.w * w.w;
  #pragma unroll
  for (int off = 32; off; off >>= 1) v += __shfl_xor(v, off);
  if (lane == 0) gatec[px] = 1.f / (1.f + expf(-(v + gb[0])));
}

// ---------------------------------------------------------------------------
// K2/K3: 1x1 conv embedding via MFMA: out_bf16[px][64] = in[px][K] @ Wt[64][K]
// Block: 256 thr = 4 waves; 64 px; each wave M=16 rows, N=64 (4 ntiles).
template <int K>
__global__ __launch_bounds__(256) void emb_mfma_kernel(
    const float* __restrict__ in, const unsigned short* __restrict__ Wt,
    const float* __restrict__ bias, unsigned short* __restrict__ out) {
  constexpr int LDA = K + 8;                  // bf16 stride; (K+8)*2 % 16 == 0
  __shared__ __align__(16) unsigned short a_s[64 * LDA];
  int t = threadIdx.x;
  int pxb = blockIdx.x * 64;

  // stage: f32 global -> bf16 LDS
  constexpr int KC = K / 4;
  for (int idx = t; idx < 64 * KC; idx += 256) {
    int px = idx / KC, kc = idx % KC;
    float4 v = *(const float4*)&in[(size_t)(pxb + px) * K + kc * 4];
    *(short4*)&a_s[px * LDA + kc * 4] =
        make_short4((short)f2b(v.x), (short)f2b(v.y), (short)f2b(v.z), (short)f2b(v.w));
  }
  __syncthreads();

  int wid = t >> 6, lane = t & 63;
  int lr = lane & 15, lg = lane >> 4;
  const f32x4 zero4 = {0.f, 0.f, 0.f, 0.f};
  f32x4 acc[4] = {zero4, zero4, zero4, zero4};

  #pragma unroll
  for (int kt = 0; kt < K / 32; kt++) {
    bf16x8 a = *(const bf16x8*)&a_s[(wid * 16 + lr) * LDA + kt * 32 + lg * 8];
    #pragma unroll
    for (int nt = 0; nt < 4; nt++) {
      bf16x8 bb = *(const bf16x8*)&Wt[(size_t)(nt * 16 + lr) * K + kt * 32 + lg * 8];
      acc[nt] = __builtin_amdgcn_mfma_f32_16x16x32_bf16(a, bb, acc[nt], 0, 0, 0);
    }
  }

  #pragma unroll
  for (int nt = 0; nt < 4; nt++) {
    int n = nt * 16 + lr;
    float bv = bias ? bias[n] : 0.f;
    #pragma unroll
    for (int r = 0; r < 4; r++) {
      int px = wid * 16 + lg * 4 + r;
      out[(size_t)(pxb + px) * 64 + n] = f2b(acc[nt][r] + bv);
    }
  }
}

// ---------------------------------------------------------------------------
// K4/K5: 3x3 content conv 64->25 via implicit-GEMM MFMA.
// Block: 256 thr = 4 waves; 8x8 px tile; K = 9 taps x 64; N = 32 (25 used).
__global__ __launch_bounds__(256) void content_mfma_kernel(
    const unsigned short* __restrict__ emb, const unsigned short* __restrict__ Wtcnt,
    const float* __restrict__ cb, float* __restrict__ out, int Hd, int Wd) {
  constexpr int LDC = 72;                      // bf16 stride per cell; 144 B, 16B-aligned
  __shared__ __align__(16) unsigned short a_s[100 * LDC];
  int t = threadIdx.x;
  int b = blockIdx.z;
  int i0 = blockIdx.y * 8, j0 = blockIdx.x * 8;

  // stage 10x10 halo x 64ch bf16 (8B chunks)
  for (int idx = t; idx < 100 * 16; idx += 256) {
    int cell = idx >> 4, ck = idx & 15;
    int gi = i0 - 1 + cell / 10;
    int gj = j0 - 1 + cell % 10;
    short4 v = make_short4(0, 0, 0, 0);
    if (gi >= 0 && gi < Hd && gj >= 0 && gj < Wd)
      v = *(const short4*)&emb[(size_t)((b * Hd + gi) * Wd + gj) * 64 + ck * 4];
    *(short4*)&a_s[cell * LDC + ck * 4] = v;
  }
  __syncthreads();

  int wid = t >> 6, lane = t & 63;
  int lr = lane & 15, lg = lane >> 4;
  int px = wid * 16 + lr;                      // A-row this lane reads
  int pi = px >> 3, pj = px & 7;
  const f32x4 zero4 = {0.f, 0.f, 0.f, 0.f};
  f32x4 acc[2] = {zero4, zero4};

  #pragma unroll
  for (int di = 0; di < 3; di++) {
    #pragma unroll
    for (int dj = 0; dj < 3; dj++) {
      int cell = (pi + di) * 10 + (pj + dj);
      int tap = di * 3 + dj;
      #pragma unroll
      for (int kt = 0; kt < 2; kt++) {
        bf16x8 a = *(const bf16x8*)&a_s[cell * LDC + kt * 32 + lg * 8];
        #pragma unroll
        for (int nt = 0; nt < 2; nt++) {
          bf16x8 bb = *(const bf16x8*)&Wtcnt[(size_t)(nt * 16 + lr) * 576 + tap * 64 + kt * 32 + lg * 8];
          acc[nt] = __builtin_amdgcn_mfma_f32_16x16x32_bf16(a, bb, acc[nt], 0, 0, 0);
        }
      }
    }
  }

  #pragma unroll
  for (int nt = 0; nt < 2; nt++) {
    int ch = nt * 16 + lr;
    if (ch < 25) {
      float bv = cb[ch];
      #pragma unroll
      for (int r = 0; r < 4; r++) {
        int opx = wid * 16 + lg * 4 + r;       // C/D row -> pixel
        int gi = i0 + (opx >> 3), gj = j0 + (opx & 7);
        out[(size_t)((b * Hd + gi) * Wd + gj) * 25 + ch] = acc[nt][r] + bv;
      }
    }
  }
}

// ---------------------------------------------------------------------------
// K6: fused softmax + CARAFE(MFMA) + proj1(MFMA) + proj2(MFMA) + gated mix.
__global__ __launch_bounds__(256) void fuse_mfma_kernel(
    const float* __restrict__ coarse, const float* __restrict__ kff,
    const float* __restrict__ kfc, const float* __restrict__ gatec,
    const unsigned short* __restrict__ Wt1, const float* __restrict__ b1,
    const unsigned short* __restrict__ Wt2, const float* __restrict__ b2,
    float* __restrict__ out) {
  __shared__ __align__(16) unsigned short buf[256 * 72];   // 36864 B
  __shared__ __align__(16) unsigned short m_ext[32 * 72];  // 4608 B
  __shared__ float g_s[32];
  unsigned short* win_t = buf;   // [ch 0..255][tap 0..63(+pad)]
  unsigned short* cu_s  = buf;   // later: [px 0..31][ch, stride 264]

  int t = threadIdx.x;
  int b = blockIdx.z;
  int i0 = blockIdx.y * 4, j0 = blockIdx.x * 8;
  int hw0 = (i0 >> 1) - 2, ww0 = (j0 >> 1) - 2;

  // ---- phase A: stage 6x8 coarse window (thread t = channel t), masks ----
  {
    #pragma unroll
    for (int p0 = 0; p0 < 48; p0 += 4) {
      unsigned short vals[4];
      #pragma unroll
      for (int q = 0; q < 4; q++) {
        int p = p0 + q;
        int h = hw0 + (p >> 3), w = ww0 + (p & 7);
        float v = 0.f;
        if (h >= 0 && h < 64 && w >= 0 && w < 64)
          v = coarse[(size_t)((b * 64 + h) * 64 + w) * 256 + t];
        vals[q] = f2b(v);
      }
      *(short4*)&win_t[t * 72 + p0] =
          make_short4((short)vals[0], (short)vals[1], (short)vals[2], (short)vals[3]);
    }
    short4 z4 = make_short4(0, 0, 0, 0);
    *(short4*)&win_t[t * 72 + 48] = z4;
    *(short4*)&win_t[t * 72 + 52] = z4;
    *(short4*)&win_t[t * 72 + 56] = z4;
    *(short4*)&win_t[t * 72 + 60] = z4;
  }
  if (t < 32) {
    int i = i0 + (t >> 3), j = j0 + (t & 7);
    size_t fpx = (size_t)((b * 128 + i) * 128 + j);
    size_t cpx = (size_t)((b * 64 + (i >> 1)) * 64 + (j >> 1));
    float v[25];
    float mx = -1e30f;
    #pragma unroll
    for (int m = 0; m < 25; m++) {
      v[m] = kff[fpx * 25 + m] + kfc[cpx * 25 + m];
      mx = fmaxf(mx, v[m]);
    }
    float s = 0.f;
    #pragma unroll
    for (int m = 0; m < 25; m++) { v[m] = expf(v[m] - mx); s += v[m]; }
    float inv = 1.f / s;
    unsigned* row32 = (unsigned*)&m_ext[t * 72];
    #pragma unroll
    for (int q = 0; q < 36; q++) row32[q] = 0;
    int wib = (t >> 3) >> 1, wjb = (t & 7) >> 1;
    #pragma unroll
    for (int di = 0; di < 5; di++)
      #pragma unroll
      for (int dj = 0; dj < 5; dj++)
        m_ext[t * 72 + (wib + di) * 8 + (wjb + dj)] = f2b(v[di * 5 + dj] * inv);
    g_s[t] = gatec[cpx];
  }
  __syncthreads();

  int wid = t >> 6, lane = t & 63;
  int lr = lane & 15, lg = lane >> 4;
  const f32x4 zero4 = {0.f, 0.f, 0.f, 0.f};

  // ---- GEMM0: cu[32x256] = M_ext[32x64] @ win[64x256] ----
  f32x4 acc0[2][4];
  #pragma unroll
  for (int mi = 0; mi < 2; mi++)
    #pragma unroll
    for (int ni = 0; ni < 4; ni++) acc0[mi][ni] = zero4;
  #pragma unroll
  for (int kt = 0; kt < 2; kt++) {
    bf16x8 a0 = *(const bf16x8*)&m_ext[lr * 72 + kt * 32 + lg * 8];
    bf16x8 a1 = *(const bf16x8*)&m_ext[(16 + lr) * 72 + kt * 32 + lg * 8];
    #pragma unroll
    for (int ni = 0; ni < 4; ni++) {
      bf16x8 bb = *(const bf16x8*)&win_t[(size_t)(wid * 64 + ni * 16 + lr) * 72 + kt * 32 + lg * 8];
      acc0[0][ni] = __builtin_amdgcn_mfma_f32_16x16x32_bf16(a0, bb, acc0[0][ni], 0, 0, 0);
      acc0[1][ni] = __builtin_amdgcn_mfma_f32_16x16x32_bf16(a1, bb, acc0[1][ni], 0, 0, 0);
    }
  }
  __syncthreads();  // all win_t reads done; buf becomes cu_s

  #pragma unroll
  for (int mi = 0; mi < 2; mi++)
    #pragma unroll
    for (int ni = 0; ni < 4; ni++)
      #pragma unroll
      for (int r = 0; r < 4; r++)
        cu_s[(mi * 16 + lg * 4 + r) * 264 + wid * 64 + ni * 16 + lr] = f2b(acc0[mi][ni][r]);
  __syncthreads();

  // ---- GEMM1: c_out = cu @ W1 + b1 (A from LDS, B from global bf16 Wt1) ----
  f32x4 acc1[2][4];
  #pragma unroll
  for (int mi = 0; mi < 2; mi++)
    #pragma unroll
    for (int ni = 0; ni < 4; ni++) acc1[mi][ni] = zero4;
  #pragma unroll 2
  for (int kt = 0; kt < 8; kt++) {
    bf16x8 a0 = *(const bf16x8*)&cu_s[lr * 264 + kt * 32 + lg * 8];
    bf16x8 a1 = *(const bf16x8*)&cu_s[(16 + lr) * 264 + kt * 32 + lg * 8];
    #pragma unroll
    for (int ni = 0; ni < 4; ni++) {
      bf16x8 bb = *(const bf16x8*)&Wt1[(size_t)(wid * 64 + ni * 16 + lr) * 256 + kt * 32 + lg * 8];
      acc1[0][ni] = __builtin_amdgcn_mfma_f32_16x16x32_bf16(a0, bb, acc1[0][ni], 0, 0, 0);
      acc1[1][ni] = __builtin_amdgcn_mfma_f32_16x16x32_bf16(a1, bb, acc1[1][ni], 0, 0, 0);
    }
  }
  float b1v[4];
  #pragma unroll
  for (int ni = 0; ni < 4; ni++) b1v[ni] = b1[wid * 64 + ni * 16 + lr];
  __syncthreads();  // all cu_s reads done

  #pragma unroll
  for (int mi = 0; mi < 2; mi++)
    #pragma unroll
    for (int ni = 0; ni < 4; ni++)
      #pragma unroll
      for (int r = 0; r < 4; r++)
        cu_s[(mi * 16 + lg * 4 + r) * 264 + wid * 64 + ni * 16 + lr] =
            f2b(acc1[mi][ni][r] + b1v[ni]);
  __syncthreads();

  // ---- GEMM2: f_out = c_out @ W2 + b2 ----
  f32x4 acc2[2][4];
  #pragma unroll
  for (int mi = 0; mi < 2; mi++)
    #pragma unroll
    for (int ni = 0; ni < 4; ni++) acc2[mi][ni] = zero4;
  #pragma unroll 2
  for (int kt = 0; kt < 8; kt++) {
    bf16x8 a0 = *(const bf16x8*)&cu_s[lr * 264 + kt * 32 + lg * 8];
    bf16x8 a1 = *(const bf16x8*)&cu_s[(16 + lr) * 264 + kt * 32 + lg * 8];
    #pragma unroll
    for (int ni = 0; ni < 4; ni++) {
      bf16x8 bb = *(const bf16x8*)&Wt2[(size_t)(wid * 64 + ni * 16 + lr) * 256 + kt * 32 + lg * 8];
      acc2[0][ni] = __builtin_amdgcn_mfma_f32_16x16x32_bf16(a0, bb, acc2[0][ni], 0, 0, 0);
      acc2[1][ni] = __builtin_amdgcn_mfma_f32_16x16x32_bf16(a1, bb, acc2[1][ni], 0, 0, 0);
    }
  }
  float b2v[4];
  #pragma unroll
  for (int ni = 0; ni < 4; ni++) b2v[ni] = b2[wid * 64 + ni * 16 + lr];

  // ---- mix + store: out = g*f_out + (1-g)*c_out ----
  #pragma unroll
  for (int mi = 0; mi < 2; mi++)
    #pragma unroll
    for (int ni = 0; ni < 4; ni++)
      #pragma unroll
      for (int r = 0; r < 4; r++) {
        int px = mi * 16 + lg * 4 + r;
        float g = g_s[px];
        int i = i0 + (px >> 3), j = j0 + (px & 7);
        float c_out = acc1[mi][ni][r] + b1v[ni];
        float f_out = acc2[mi][ni][r] + b2v[ni];
        out[(size_t)((b * 128 + i) * 128 + j) * 256 + wid * 64 + ni * 16 + lr] =
            g * f_out + (1.f - g) * c_out;
      }
}

// ---------------------------------------------------------------------------
extern "C" void kernel_launch(void* const* d_in, const int* in_sizes, int n_in,
                              void* d_out, int out_size, void* d_ws, size_t ws_size,
                              hipStream_t stream) {
  const float* fine        = (const float*)d_in[0];
  const float* coarse      = (const float*)d_in[1];
  const float* gate_w      = (const float*)d_in[2];
  const float* gate_b      = (const float*)d_in[3];
  const float* ss_fine_w   = (const float*)d_in[4];
  const float* ss_fine_b   = (const float*)d_in[5];
  const float* ss_coarse_w = (const float*)d_in[6];
  const float* ss_content_w= (const float*)d_in[7];
  const float* ss_content_b= (const float*)d_in[8];
  const float* W1          = (const float*)d_in[9];
  const float* b1          = (const float*)d_in[10];
  const float* W2          = (const float*)d_in[11];
  const float* b2          = (const float*)d_in[12];
  float* out = (float*)d_out;

  char* ws = (char*)d_ws;
  size_t off = 0;
  float* gatec = (float*)(ws + off); off += 131072;
  unsigned short* femb = (unsigned short*)(ws + off); off += (size_t)Nf * 64 * 2;
  unsigned short* cemb = (unsigned short*)(ws + off); off += (size_t)Nc * 64 * 2;
  float* kff   = (float*)(ws + off); off += (size_t)Nf * 25 * 4;
  float* kfc   = (float*)(ws + off); off += (size_t)Nc * 25 * 4;
  unsigned short* Wt1 = (unsigned short*)(ws + off); off += 65536 * 2;
  unsigned short* Wt2 = (unsigned short*)(ws + off); off += 65536 * 2;
  unsigned short* Wtf = (unsigned short*)(ws + off); off += 64 * 128 * 2;
  unsigned short* Wtc = (unsigned short*)(ws + off); off += 64 * 256 * 2;
  unsigned short* Wtcnt = (unsigned short*)(ws + off); off += 32 * 576 * 2;

  wprep_kernel<<<dim3(4, 4, 2), 256, 0, stream>>>(W1, W2, Wt1, Wt2);
  sprep_kernel<<<3, 256, 0, stream>>>(ss_fine_w, ss_coarse_w, ss_content_w, Wtf, Wtc, Wtcnt);
  gate_kernel<<<Nc / 4, 256, 0, stream>>>(coarse, gate_w, gate_b, gatec);
  emb_mfma_kernel<128><<<Nf / 64, 256, 0, stream>>>(fine, Wtf, ss_fine_b, femb);
  emb_mfma_kernel<256><<<Nc / 64, 256, 0, stream>>>(coarse, Wtc, nullptr, cemb);
  content_mfma_kernel<<<dim3(Wf / 8, Hf / 8, Bb), 256, 0, stream>>>(femb, Wtcnt, ss_content_b, kff, Hf, Wf);
  content_mfma_kernel<<<dim3(Wc / 8, Hc / 8, Bb), 256, 0, stream>>>(cemb, Wtcnt, ss_content_b, kfc, Hc, Wc);
  fuse_mfma_kernel<<<dim3(Wf / 8, Hf / 4, Bb), 256, 0, stream>>>(
      coarse, kff, kfc, gatec, Wt1, b1, Wt2, b2, out);
}

// Round 4
// 164.685 us; speedup vs baseline: 5.2888x; 1.1178x over previous
//
#include <hip/hip_runtime.h>
#include <math.h>

// Problem constants (fixed by setup_inputs)
constexpr int Bb = 4, Hc = 64, Wc = 64, Cc = 256, Cf = 128, E = 64, KK = 25, F = 256;
constexpr int Hf = 128, Wf = 128;
constexpr int Nc = Bb * Hc * Wc;   // 16384 coarse pixels
constexpr int Nf = Bb * Hf * Wf;   // 65536 fine pixels

typedef __attribute__((ext_vector_type(8))) short bf16x8;
typedef __attribute__((ext_vector_type(4))) float f32x4;

__device__ inline unsigned short f2b(float f) {
  union { float f; unsigned u; } v; v.f = f;
  return (unsigned short)((v.u + 0x7FFF + ((v.u >> 16) & 1)) >> 16);
}
__device__ inline float b2f(unsigned short h) {
  union { unsigned u; float f; } v; v.u = ((unsigned)h) << 16; return v.f;
}

// ---------------------------------------------------------------------------
// K0a: transpose + bf16-convert the two 256x256 projection weights: Wt[n][k]
__global__ __launch_bounds__(256) void wprep_kernel(
    const float* __restrict__ W1, const float* __restrict__ W2,
    unsigned short* __restrict__ Wt1, unsigned short* __restrict__ Wt2) {
  __shared__ float tile[64][65];
  const float* W = blockIdx.z ? W2 : W1;
  unsigned short* Wt = blockIdx.z ? Wt2 : Wt1;
  int k0 = blockIdx.x * 64, n0 = blockIdx.y * 64;
  int r0 = threadIdx.x >> 6, c = threadIdx.x & 63;
  for (int r = r0; r < 64; r += 4)
    tile[r][c] = W[(size_t)(k0 + r) * 256 + n0 + c];
  __syncthreads();
  for (int r = r0; r < 64; r += 4)
    Wt[(size_t)(n0 + r) * 256 + k0 + c] = f2b(tile[c][r]);
}

// K0b: transpose + bf16-convert small weights (emb fine/coarse, content)
__global__ __launch_bounds__(256) void sprep_kernel(
    const float* __restrict__ fw, const float* __restrict__ cw,
    const float* __restrict__ cntw, unsigned short* __restrict__ Wtf,
    unsigned short* __restrict__ Wtc, unsigned short* __restrict__ Wtcnt) {
  int t = threadIdx.x, sec = blockIdx.x;
  if (sec == 0) {
    for (int idx = t; idx < 64 * 128; idx += 256) {
      int n = idx & 63, k = idx >> 6;
      Wtf[n * 128 + k] = f2b(fw[k * 64 + n]);
    }
  } else if (sec == 1) {
    for (int idx = t; idx < 64 * 256; idx += 256) {
      int n = idx & 63, k = idx >> 6;
      Wtc[n * 256 + k] = f2b(cw[k * 64 + n]);
    }
  } else {
    for (int idx = t; idx < 32 * 576; idx += 256) {
      int n = idx & 31, kk = idx >> 5;
      Wtcnt[n * 576 + kk] = (n < 25) ? f2b(cntw[kk * 25 + n]) : (unsigned short)0;
    }
  }
}

// ---------------------------------------------------------------------------
// K1: gate = sigmoid(coarse . gate_w + gate_b)  per coarse pixel
__global__ __launch_bounds__(256) void gate_kernel(
    const float* __restrict__ coarse, const float* __restrict__ gw,
    const float* __restrict__ gb, float* __restrict__ gatec) {
  int px   = blockIdx.x * 4 + (threadIdx.x >> 6);
  int lane = threadIdx.x & 63;
  const float4 a = *(const float4*)(coarse + (size_t)px * 256 + lane * 4);
  const float4 w = *(const float4*)(gw + lane * 4);
  float v = a.x * w.x + a.y * w.y + a.z * w.z + a.w * w.w;
  #pragma unroll
  for (int off = 32; off; off >>= 1) v += __shfl_xor(v, off);
  if (lane == 0) gatec[px] = 1.f / (1.f + expf(-(v + gb[0])));
}

// ---------------------------------------------------------------------------
// K2/K3: 1x1 conv embedding via MFMA: out_bf16[px][64] = in[px][K] @ Wt[64][K]
template <int K>
__global__ __launch_bounds__(256) void emb_mfma_kernel(
    const float* __restrict__ in, const unsigned short* __restrict__ Wt,
    const float* __restrict__ bias, unsigned short* __restrict__ out) {
  constexpr int LDA = K + 8;
  __shared__ __align__(16) unsigned short a_s[64 * LDA];
  int t = threadIdx.x;
  int pxb = blockIdx.x * 64;

  constexpr int KC = K / 4;
  for (int idx = t; idx < 64 * KC; idx += 256) {
    int px = idx / KC, kc = idx % KC;
    float4 v = *(const float4*)&in[(size_t)(pxb + px) * K + kc * 4];
    *(short4*)&a_s[px * LDA + kc * 4] =
        make_short4((short)f2b(v.x), (short)f2b(v.y), (short)f2b(v.z), (short)f2b(v.w));
  }
  __syncthreads();

  int wid = t >> 6, lane = t & 63;
  int lr = lane & 15, lg = lane >> 4;
  const f32x4 zero4 = {0.f, 0.f, 0.f, 0.f};
  f32x4 acc[4] = {zero4, zero4, zero4, zero4};

  #pragma unroll
  for (int kt = 0; kt < K / 32; kt++) {
    bf16x8 a = *(const bf16x8*)&a_s[(wid * 16 + lr) * LDA + kt * 32 + lg * 8];
    #pragma unroll
    for (int nt = 0; nt < 4; nt++) {
      bf16x8 bb = *(const bf16x8*)&Wt[(size_t)(nt * 16 + lr) * K + kt * 32 + lg * 8];
      acc[nt] = __builtin_amdgcn_mfma_f32_16x16x32_bf16(a, bb, acc[nt], 0, 0, 0);
    }
  }

  #pragma unroll
  for (int nt = 0; nt < 4; nt++) {
    int n = nt * 16 + lr;
    float bv = bias ? bias[n] : 0.f;
    #pragma unroll
    for (int r = 0; r < 4; r++) {
      int px = wid * 16 + lg * 4 + r;
      out[(size_t)(pxb + px) * 64 + n] = f2b(acc[nt][r] + bv);
    }
  }
}

// ---------------------------------------------------------------------------
// K4/K5: 3x3 content conv 64->25 via implicit-GEMM MFMA.
__global__ __launch_bounds__(256) void content_mfma_kernel(
    const unsigned short* __restrict__ emb, const unsigned short* __restrict__ Wtcnt,
    const float* __restrict__ cb, float* __restrict__ out, int Hd, int Wd) {
  constexpr int LDC = 72;
  __shared__ __align__(16) unsigned short a_s[100 * LDC];
  int t = threadIdx.x;
  int b = blockIdx.z;
  int i0 = blockIdx.y * 8, j0 = blockIdx.x * 8;

  for (int idx = t; idx < 100 * 16; idx += 256) {
    int cell = idx >> 4, ck = idx & 15;
    int gi = i0 - 1 + cell / 10;
    int gj = j0 - 1 + cell % 10;
    short4 v = make_short4(0, 0, 0, 0);
    if (gi >= 0 && gi < Hd && gj >= 0 && gj < Wd)
      v = *(const short4*)&emb[(size_t)((b * Hd + gi) * Wd + gj) * 64 + ck * 4];
    *(short4*)&a_s[cell * LDC + ck * 4] = v;
  }
  __syncthreads();

  int wid = t >> 6, lane = t & 63;
  int lr = lane & 15, lg = lane >> 4;
  int px = wid * 16 + lr;
  int pi = px >> 3, pj = px & 7;
  const f32x4 zero4 = {0.f, 0.f, 0.f, 0.f};
  f32x4 acc[2] = {zero4, zero4};

  #pragma unroll
  for (int di = 0; di < 3; di++) {
    #pragma unroll
    for (int dj = 0; dj < 3; dj++) {
      int cell = (pi + di) * 10 + (pj + dj);
      int tap = di * 3 + dj;
      #pragma unroll
      for (int kt = 0; kt < 2; kt++) {
        bf16x8 a = *(const bf16x8*)&a_s[cell * LDC + kt * 32 + lg * 8];
        #pragma unroll
        for (int nt = 0; nt < 2; nt++) {
          bf16x8 bb = *(const bf16x8*)&Wtcnt[(size_t)(nt * 16 + lr) * 576 + tap * 64 + kt * 32 + lg * 8];
          acc[nt] = __builtin_amdgcn_mfma_f32_16x16x32_bf16(a, bb, acc[nt], 0, 0, 0);
        }
      }
    }
  }

  #pragma unroll
  for (int nt = 0; nt < 2; nt++) {
    int ch = nt * 16 + lr;
    if (ch < 25) {
      float bv = cb[ch];
      #pragma unroll
      for (int r = 0; r < 4; r++) {
        int opx = wid * 16 + lg * 4 + r;
        int gi = i0 + (opx >> 3), gj = j0 + (opx & 7);
        out[(size_t)((b * Hd + gi) * Wd + gj) * 25 + ch] = acc[nt][r] + bv;
      }
    }
  }
}

// ---------------------------------------------------------------------------
// K6a: carafe only -> cu_g bf16 [Nf][256]
__global__ __launch_bounds__(256) void carafe_kernel(
    const float* __restrict__ coarse, const float* __restrict__ kff,
    const float* __restrict__ kfc, unsigned short* __restrict__ cu_g) {
  __shared__ __align__(16) unsigned short buf[256 * 72];
  __shared__ __align__(16) unsigned short m_ext[32 * 72];
  unsigned short* win_t = buf;
  unsigned short* cu_s  = buf;

  int t = threadIdx.x;
  int b = blockIdx.z;
  int i0 = blockIdx.y * 4, j0 = blockIdx.x * 8;
  int hw0 = (i0 >> 1) - 2, ww0 = (j0 >> 1) - 2;

  {
    #pragma unroll
    for (int p0 = 0; p0 < 48; p0 += 4) {
      unsigned short vals[4];
      #pragma unroll
      for (int q = 0; q < 4; q++) {
        int p = p0 + q;
        int h = hw0 + (p >> 3), w = ww0 + (p & 7);
        float v = 0.f;
        if (h >= 0 && h < 64 && w >= 0 && w < 64)
          v = coarse[(size_t)((b * 64 + h) * 64 + w) * 256 + t];
        vals[q] = f2b(v);
      }
      *(short4*)&win_t[t * 72 + p0] =
          make_short4((short)vals[0], (short)vals[1], (short)vals[2], (short)vals[3]);
    }
    short4 z4 = make_short4(0, 0, 0, 0);
    *(short4*)&win_t[t * 72 + 48] = z4;
    *(short4*)&win_t[t * 72 + 52] = z4;
    *(short4*)&win_t[t * 72 + 56] = z4;
    *(short4*)&win_t[t * 72 + 60] = z4;
  }
  if (t < 32) {
    int i = i0 + (t >> 3), j = j0 + (t & 7);
    size_t fpx = (size_t)((b * 128 + i) * 128 + j);
    size_t cpx = (size_t)((b * 64 + (i >> 1)) * 64 + (j >> 1));
    float v[25];
    float mx = -1e30f;
    #pragma unroll
    for (int m = 0; m < 25; m++) {
      v[m] = kff[fpx * 25 + m] + kfc[cpx * 25 + m];
      mx = fmaxf(mx, v[m]);
    }
    float s = 0.f;
    #pragma unroll
    for (int m = 0; m < 25; m++) { v[m] = expf(v[m] - mx); s += v[m]; }
    float inv = 1.f / s;
    unsigned* row32 = (unsigned*)&m_ext[t * 72];
    #pragma unroll
    for (int q = 0; q < 36; q++) row32[q] = 0;
    int wib = (t >> 3) >> 1, wjb = (t & 7) >> 1;
    #pragma unroll
    for (int di = 0; di < 5; di++)
      #pragma unroll
      for (int dj = 0; dj < 5; dj++)
        m_ext[t * 72 + (wib + di) * 8 + (wjb + dj)] = f2b(v[di * 5 + dj] * inv);
  }
  __syncthreads();

  int wid = t >> 6, lane = t & 63;
  int lr = lane & 15, lg = lane >> 4;
  const f32x4 zero4 = {0.f, 0.f, 0.f, 0.f};

  f32x4 acc0[2][4];
  #pragma unroll
  for (int mi = 0; mi < 2; mi++)
    #pragma unroll
    for (int ni = 0; ni < 4; ni++) acc0[mi][ni] = zero4;
  #pragma unroll
  for (int kt = 0; kt < 2; kt++) {
    bf16x8 a0 = *(const bf16x8*)&m_ext[lr * 72 + kt * 32 + lg * 8];
    bf16x8 a1 = *(const bf16x8*)&m_ext[(16 + lr) * 72 + kt * 32 + lg * 8];
    #pragma unroll
    for (int ni = 0; ni < 4; ni++) {
      bf16x8 bb = *(const bf16x8*)&win_t[(size_t)(wid * 64 + ni * 16 + lr) * 72 + kt * 32 + lg * 8];
      acc0[0][ni] = __builtin_amdgcn_mfma_f32_16x16x32_bf16(a0, bb, acc0[0][ni], 0, 0, 0);
      acc0[1][ni] = __builtin_amdgcn_mfma_f32_16x16x32_bf16(a1, bb, acc0[1][ni], 0, 0, 0);
    }
  }
  __syncthreads();  // win_t reads done; buf becomes cu_s

  #pragma unroll
  for (int mi = 0; mi < 2; mi++)
    #pragma unroll
    for (int ni = 0; ni < 4; ni++)
      #pragma unroll
      for (int r = 0; r < 4; r++)
        cu_s[(mi * 16 + lg * 4 + r) * 264 + wid * 64 + ni * 16 + lr] = f2b(acc0[mi][ni][r]);
  __syncthreads();

  // coalesced copy LDS -> global (32 px x 256 ch bf16)
  for (int c = t; c < 1024; c += 256) {
    int p = c >> 5, off = (c & 31) << 3;
    int gi = i0 + (p >> 3), gj = j0 + (p & 7);
    bf16x8 v = *(const bf16x8*)&cu_s[p * 264 + off];
    *(bf16x8*)&cu_g[(size_t)((b * 128 + gi) * 128 + gj) * 256 + off] = v;
  }
}

// ---------------------------------------------------------------------------
// K6b: chained projections + gated mix. M=128 rows (one fine image row)/block.
__global__ __launch_bounds__(256) void proj_kernel(
    const unsigned short* __restrict__ cu_g, const float* __restrict__ gatec,
    const unsigned short* __restrict__ Wt1, const float* __restrict__ b1,
    const unsigned short* __restrict__ Wt2, const float* __restrict__ b2,
    float* __restrict__ out) {
  __shared__ __align__(16) unsigned short a_s[128 * 264];  // 67584 B, reused for c_out
  __shared__ float g_s[64];
  int t = threadIdx.x;
  size_t m0 = (size_t)blockIdx.x * 128;
  int bb_ = blockIdx.x >> 7;      // batch
  int ii  = blockIdx.x & 127;     // fine row i

  for (int c = t; c < 4096; c += 256) {
    int row = c >> 5, off = (c & 31) << 3;
    *(bf16x8*)&a_s[row * 264 + off] = *(const bf16x8*)&cu_g[(m0 + row) * 256 + off];
  }
  if (t < 64) g_s[t] = gatec[(size_t)(bb_ * 64 + (ii >> 1)) * 64 + t];
  __syncthreads();

  int wid = t >> 6, lane = t & 63;
  int lr = lane & 15, lg = lane >> 4;
  const f32x4 zero4 = {0.f, 0.f, 0.f, 0.f};
  f32x4 acc[8][4];

  // ---- GEMM1: c_out = cu @ W1 + b1 ----
  #pragma unroll
  for (int mt = 0; mt < 8; mt++)
    #pragma unroll
    for (int ni = 0; ni < 4; ni++) acc[mt][ni] = zero4;
  #pragma unroll 2
  for (int kt = 0; kt < 8; kt++) {
    bf16x8 a[8];
    #pragma unroll
    for (int mt = 0; mt < 8; mt++)
      a[mt] = *(const bf16x8*)&a_s[(mt * 16 + lr) * 264 + kt * 32 + lg * 8];
    #pragma unroll
    for (int ni = 0; ni < 4; ni++) {
      bf16x8 bb = *(const bf16x8*)&Wt1[(size_t)(wid * 64 + ni * 16 + lr) * 256 + kt * 32 + lg * 8];
      #pragma unroll
      for (int mt = 0; mt < 8; mt++)
        acc[mt][ni] = __builtin_amdgcn_mfma_f32_16x16x32_bf16(a[mt], bb, acc[mt][ni], 0, 0, 0);
    }
  }
  float b1v[4];
  #pragma unroll
  for (int ni = 0; ni < 4; ni++) b1v[ni] = b1[wid * 64 + ni * 16 + lr];
  __syncthreads();  // all GEMM1 reads done

  #pragma unroll
  for (int mt = 0; mt < 8; mt++)
    #pragma unroll
    for (int ni = 0; ni < 4; ni++)
      #pragma unroll
      for (int r = 0; r < 4; r++)
        a_s[(mt * 16 + lg * 4 + r) * 264 + wid * 64 + ni * 16 + lr] =
            f2b(acc[mt][ni][r] + b1v[ni]);
  __syncthreads();

  // ---- GEMM2: f_out = c_out @ W2 + b2 (reuse acc registers) ----
  #pragma unroll
  for (int mt = 0; mt < 8; mt++)
    #pragma unroll
    for (int ni = 0; ni < 4; ni++) acc[mt][ni] = zero4;
  #pragma unroll 2
  for (int kt = 0; kt < 8; kt++) {
    bf16x8 a[8];
    #pragma unroll
    for (int mt = 0; mt < 8; mt++)
      a[mt] = *(const bf16x8*)&a_s[(mt * 16 + lr) * 264 + kt * 32 + lg * 8];
    #pragma unroll
    for (int ni = 0; ni < 4; ni++) {
      bf16x8 bb = *(const bf16x8*)&Wt2[(size_t)(wid * 64 + ni * 16 + lr) * 256 + kt * 32 + lg * 8];
      #pragma unroll
      for (int mt = 0; mt < 8; mt++)
        acc[mt][ni] = __builtin_amdgcn_mfma_f32_16x16x32_bf16(a[mt], bb, acc[mt][ni], 0, 0, 0);
    }
  }
  float b2v[4];
  #pragma unroll
  for (int ni = 0; ni < 4; ni++) b2v[ni] = b2[wid * 64 + ni * 16 + lr];

  // ---- mix + store ----
  #pragma unroll
  for (int mt = 0; mt < 8; mt++) {
    #pragma unroll
    for (int r = 0; r < 4; r++) {
      int row = mt * 16 + lg * 4 + r;
      float g = g_s[row >> 1];
      size_t obase = (m0 + row) * 256;
      #pragma unroll
      for (int ni = 0; ni < 4; ni++) {
        int col = wid * 64 + ni * 16 + lr;
        float f_out = acc[mt][ni][r] + b2v[ni];
        float c_outv = b2f(a_s[row * 264 + col]);
        out[obase + col] = g * f_out + (1.f - g) * c_outv;
      }
    }
  }
}

// ---------------------------------------------------------------------------
// Fallback: R2's fully-fused kernel (used only if ws is too small for cu_g)
__global__ __launch_bounds__(256) void fuse_mfma_kernel(
    const float* __restrict__ coarse, const float* __restrict__ kff,
    const float* __restrict__ kfc, const float* __restrict__ gatec,
    const unsigned short* __restrict__ Wt1, const float* __restrict__ b1,
    const unsigned short* __restrict__ Wt2, const float* __restrict__ b2,
    float* __restrict__ out) {
  __shared__ __align__(16) unsigned short buf[256 * 72];
  __shared__ __align__(16) unsigned short m_ext[32 * 72];
  __shared__ float g_s[32];
  unsigned short* win_t = buf;
  unsigned short* cu_s  = buf;

  int t = threadIdx.x;
  int b = blockIdx.z;
  int i0 = blockIdx.y * 4, j0 = blockIdx.x * 8;
  int hw0 = (i0 >> 1) - 2, ww0 = (j0 >> 1) - 2;

  {
    #pragma unroll
    for (int p0 = 0; p0 < 48; p0 += 4) {
      unsigned short vals[4];
      #pragma unroll
      for (int q = 0; q < 4; q++) {
        int p = p0 + q;
        int h = hw0 + (p >> 3), w = ww0 + (p & 7);
        float v = 0.f;
        if (h >= 0 && h < 64 && w >= 0 && w < 64)
          v = coarse[(size_t)((b * 64 + h) * 64 + w) * 256 + t];
        vals[q] = f2b(v);
      }
      *(short4*)&win_t[t * 72 + p0] =
          make_short4((short)vals[0], (short)vals[1], (short)vals[2], (short)vals[3]);
    }
    short4 z4 = make_short4(0, 0, 0, 0);
    *(short4*)&win_t[t * 72 + 48] = z4;
    *(short4*)&win_t[t * 72 + 52] = z4;
    *(short4*)&win_t[t * 72 + 56] = z4;
    *(short4*)&win_t[t * 72 + 60] = z4;
  }
  if (t < 32) {
    int i = i0 + (t >> 3), j = j0 + (t & 7);
    size_t fpx = (size_t)((b * 128 + i) * 128 + j);
    size_t cpx = (size_t)((b * 64 + (i >> 1)) * 64 + (j >> 1));
    float v[25];
    float mx = -1e30f;
    #pragma unroll
    for (int m = 0; m < 25; m++) {
      v[m] = kff[fpx * 25 + m] + kfc[cpx * 25 + m];
      mx = fmaxf(mx, v[m]);
    }
    float s = 0.f;
    #pragma unroll
    for (int m = 0; m < 25; m++) { v[m] = expf(v[m] - mx); s += v[m]; }
    float inv = 1.f / s;
    unsigned* row32 = (unsigned*)&m_ext[t * 72];
    #pragma unroll
    for (int q = 0; q < 36; q++) row32[q] = 0;
    int wib = (t >> 3) >> 1, wjb = (t & 7) >> 1;
    #pragma unroll
    for (int di = 0; di < 5; di++)
      #pragma unroll
      for (int dj = 0; dj < 5; dj++)
        m_ext[t * 72 + (wib + di) * 8 + (wjb + dj)] = f2b(v[di * 5 + dj] * inv);
    g_s[t] = gatec[cpx];
  }
  __syncthreads();

  int wid = t >> 6, lane = t & 63;
  int lr = lane & 15, lg = lane >> 4;
  const f32x4 zero4 = {0.f, 0.f, 0.f, 0.f};

  f32x4 acc0[2][4];
  #pragma unroll
  for (int mi = 0; mi < 2; mi++)
    #pragma unroll
    for (int ni = 0; ni < 4; ni++) acc0[mi][ni] = zero4;
  #pragma unroll
  for (int kt = 0; kt < 2; kt++) {
    bf16x8 a0 = *(const bf16x8*)&m_ext[lr * 72 + kt * 32 + lg * 8];
    bf16x8 a1 = *(const bf16x8*)&m_ext[(16 + lr) * 72 + kt * 32 + lg * 8];
    #pragma unroll
    for (int ni = 0; ni < 4; ni++) {
      bf16x8 bb = *(const bf16x8*)&win_t[(size_t)(wid * 64 + ni * 16 + lr) * 72 + kt * 32 + lg * 8];
      acc0[0][ni] = __builtin_amdgcn_mfma_f32_16x16x32_bf16(a0, bb, acc0[0][ni], 0, 0, 0);
      acc0[1][ni] = __builtin_amdgcn_mfma_f32_16x16x32_bf16(a1, bb, acc0[1][ni], 0, 0, 0);
    }
  }
  __syncthreads();

  #pragma unroll
  for (int mi = 0; mi < 2; mi++)
    #pragma unroll
    for (int ni = 0; ni < 4; ni++)
      #pragma unroll
      for (int r = 0; r < 4; r++)
        cu_s[(mi * 16 + lg * 4 + r) * 264 + wid * 64 + ni * 16 + lr] = f2b(acc0[mi][ni][r]);
  __syncthreads();

  f32x4 acc1[2][4];
  #pragma unroll
  for (int mi = 0; mi < 2; mi++)
    #pragma unroll
    for (int ni = 0; ni < 4; ni++) acc1[mi][ni] = zero4;
  #pragma unroll 2
  for (int kt = 0; kt < 8; kt++) {
    bf16x8 a0 = *(const bf16x8*)&cu_s[lr * 264 + kt * 32 + lg * 8];
    bf16x8 a1 = *(const bf16x8*)&cu_s[(16 + lr) * 264 + kt * 32 + lg * 8];
    #pragma unroll
    for (int ni = 0; ni < 4; ni++) {
      bf16x8 bb = *(const bf16x8*)&Wt1[(size_t)(wid * 64 + ni * 16 + lr) * 256 + kt * 32 + lg * 8];
      acc1[0][ni] = __builtin_amdgcn_mfma_f32_16x16x32_bf16(a0, bb, acc1[0][ni], 0, 0, 0);
      acc1[1][ni] = __builtin_amdgcn_mfma_f32_16x16x32_bf16(a1, bb, acc1[1][ni], 0, 0, 0);
    }
  }
  float b1v[4];
  #pragma unroll
  for (int ni = 0; ni < 4; ni++) b1v[ni] = b1[wid * 64 + ni * 16 + lr];
  __syncthreads();

  #pragma unroll
  for (int mi = 0; mi < 2; mi++)
    #pragma unroll
    for (int ni = 0; ni < 4; ni++)
      #pragma unroll
      for (int r = 0; r < 4; r++)
        cu_s[(mi * 16 + lg * 4 + r) * 264 + wid * 64 + ni * 16 + lr] =
            f2b(acc1[mi][ni][r] + b1v[ni]);
  __syncthreads();

  f32x4 acc2[2][4];
  #pragma unroll
  for (int mi = 0; mi < 2; mi++)
    #pragma unroll
    for (int ni = 0; ni < 4; ni++) acc2[mi][ni] = zero4;
  #pragma unroll 2
  for (int kt = 0; kt < 8; kt++) {
    bf16x8 a0 = *(const bf16x8*)&cu_s[lr * 264 + kt * 32 + lg * 8];
    bf16x8 a1 = *(const bf16x8*)&cu_s[(16 + lr) * 264 + kt * 32 + lg * 8];
    #pragma unroll
    for (int ni = 0; ni < 4; ni++) {
      bf16x8 bb = *(const bf16x8*)&Wt2[(size_t)(wid * 64 + ni * 16 + lr) * 256 + kt * 32 + lg * 8];
      acc2[0][ni] = __builtin_amdgcn_mfma_f32_16x16x32_bf16(a0, bb, acc2[0][ni], 0, 0, 0);
      acc2[1][ni] = __builtin_amdgcn_mfma_f32_16x16x32_bf16(a1, bb, acc2[1][ni], 0, 0, 0);
    }
  }
  float b2v[4];
  #pragma unroll
  for (int ni = 0; ni < 4; ni++) b2v[ni] = b2[wid * 64 + ni * 16 + lr];

  #pragma unroll
  for (int mi = 0; mi < 2; mi++)
    #pragma unroll
    for (int ni = 0; ni < 4; ni++)
      #pragma unroll
      for (int r = 0; r < 4; r++) {
        int px = mi * 16 + lg * 4 + r;
        float g = g_s[px];
        int i = i0 + (px >> 3), j = j0 + (px & 7);
        float c_out = acc1[mi][ni][r] + b1v[ni];
        float f_out = acc2[mi][ni][r] + b2v[ni];
        out[(size_t)((b * 128 + i) * 128 + j) * 256 + wid * 64 + ni * 16 + lr] =
            g * f_out + (1.f - g) * c_out;
      }
}

// ---------------------------------------------------------------------------
extern "C" void kernel_launch(void* const* d_in, const int* in_sizes, int n_in,
                              void* d_out, int out_size, void* d_ws, size_t ws_size,
                              hipStream_t stream) {
  const float* fine        = (const float*)d_in[0];
  const float* coarse      = (const float*)d_in[1];
  const float* gate_w      = (const float*)d_in[2];
  const float* gate_b      = (const float*)d_in[3];
  const float* ss_fine_w   = (const float*)d_in[4];
  const float* ss_fine_b   = (const float*)d_in[5];
  const float* ss_coarse_w = (const float*)d_in[6];
  const float* ss_content_w= (const float*)d_in[7];
  const float* ss_content_b= (const float*)d_in[8];
  const float* W1          = (const float*)d_in[9];
  const float* b1          = (const float*)d_in[10];
  const float* W2          = (const float*)d_in[11];
  const float* b2          = (const float*)d_in[12];
  float* out = (float*)d_out;

  char* ws = (char*)d_ws;
  size_t off = 0;
  float* gatec = (float*)(ws + off); off += 131072;
  unsigned short* femb = (unsigned short*)(ws + off); off += (size_t)Nf * 64 * 2;
  unsigned short* cemb = (unsigned short*)(ws + off); off += (size_t)Nc * 64 * 2;
  float* kff   = (float*)(ws + off); off += (size_t)Nf * 25 * 4;
  float* kfc   = (float*)(ws + off); off += (size_t)Nc * 25 * 4;
  unsigned short* Wt1 = (unsigned short*)(ws + off); off += 65536 * 2;
  unsigned short* Wt2 = (unsigned short*)(ws + off); off += 65536 * 2;
  unsigned short* Wtf = (unsigned short*)(ws + off); off += 64 * 128 * 2;
  unsigned short* Wtc = (unsigned short*)(ws + off); off += 64 * 256 * 2;
  unsigned short* Wtcnt = (unsigned short*)(ws + off); off += 32 * 576 * 2;
  unsigned short* cu_g = (unsigned short*)(ws + off); off += (size_t)Nf * 256 * 2;
  bool split = (ws_size >= off);

  wprep_kernel<<<dim3(4, 4, 2), 256, 0, stream>>>(W1, W2, Wt1, Wt2);
  sprep_kernel<<<3, 256, 0, stream>>>(ss_fine_w, ss_coarse_w, ss_content_w, Wtf, Wtc, Wtcnt);
  gate_kernel<<<Nc / 4, 256, 0, stream>>>(coarse, gate_w, gate_b, gatec);
  emb_mfma_kernel<128><<<Nf / 64, 256, 0, stream>>>(fine, Wtf, ss_fine_b, femb);
  emb_mfma_kernel<256><<<Nc / 64, 256, 0, stream>>>(coarse, Wtc, nullptr, cemb);
  content_mfma_kernel<<<dim3(Wf / 8, Hf / 8, Bb), 256, 0, stream>>>(femb, Wtcnt, ss_content_b, kff, Hf, Wf);
  content_mfma_kernel<<<dim3(Wc / 8, Hc / 8, Bb), 256, 0, stream>>>(cemb, Wtcnt, ss_content_b, kfc, Hc, Wc);
  if (split) {
    carafe_kernel<<<dim3(Wf / 8, Hf / 4, Bb), 256, 0, stream>>>(coarse, kff, kfc, cu_g);
    proj_kernel<<<Nf / 128, 256, 0, stream>>>(cu_g, gatec, Wt1, b1, Wt2, b2, out);
  } else {
    fuse_mfma_kernel<<<dim3(Wf / 8, Hf / 4, Bb), 256, 0, stream>>>(
        coarse, kff, kfc, gatec, Wt1, b1, Wt2, b2, out);
  }
}

// Round 5
// 163.781 us; speedup vs baseline: 5.3180x; 1.0055x over previous
//
#include <hip/hip_runtime.h>
#include <math.h>

// Problem constants (fixed by setup_inputs)
constexpr int Bb = 4, Hc = 64, Wc = 64, Cc = 256, Cf = 128, E = 64, KK = 25, F = 256;
constexpr int Hf = 128, Wf = 128;
constexpr int Nc = Bb * Hc * Wc;   // 16384 coarse pixels
constexpr int Nf = Bb * Hf * Wf;   // 65536 fine pixels

typedef __attribute__((ext_vector_type(8))) short bf16x8;
typedef __attribute__((ext_vector_type(4))) float f32x4;

__device__ inline unsigned short f2b(float f) {
  union { float f; unsigned u; } v; v.f = f;
  return (unsigned short)((v.u + 0x7FFF + ((v.u >> 16) & 1)) >> 16);
}
__device__ inline float b2f(unsigned short h) {
  union { unsigned u; float f; } v; v.u = ((unsigned)h) << 16; return v.f;
}

// ---------------------------------------------------------------------------
// K0a: transpose + bf16-convert the two 256x256 projection weights: Wt[n][k]
__global__ __launch_bounds__(256) void wprep_kernel(
    const float* __restrict__ W1, const float* __restrict__ W2,
    unsigned short* __restrict__ Wt1, unsigned short* __restrict__ Wt2) {
  __shared__ float tile[64][65];
  const float* W = blockIdx.z ? W2 : W1;
  unsigned short* Wt = blockIdx.z ? Wt2 : Wt1;
  int k0 = blockIdx.x * 64, n0 = blockIdx.y * 64;
  int r0 = threadIdx.x >> 6, c = threadIdx.x & 63;
  for (int r = r0; r < 64; r += 4)
    tile[r][c] = W[(size_t)(k0 + r) * 256 + n0 + c];
  __syncthreads();
  for (int r = r0; r < 64; r += 4)
    Wt[(size_t)(n0 + r) * 256 + k0 + c] = f2b(tile[c][r]);
}

// K0b: transpose + bf16-convert small weights (emb fine/coarse, content)
__global__ __launch_bounds__(256) void sprep_kernel(
    const float* __restrict__ fw, const float* __restrict__ cw,
    const float* __restrict__ cntw, unsigned short* __restrict__ Wtf,
    unsigned short* __restrict__ Wtc, unsigned short* __restrict__ Wtcnt) {
  int t = threadIdx.x, sec = blockIdx.x;
  if (sec == 0) {
    for (int idx = t; idx < 64 * 128; idx += 256) {
      int n = idx & 63, k = idx >> 6;
      Wtf[n * 128 + k] = f2b(fw[k * 64 + n]);
    }
  } else if (sec == 1) {
    for (int idx = t; idx < 64 * 256; idx += 256) {
      int n = idx & 63, k = idx >> 6;
      Wtc[n * 256 + k] = f2b(cw[k * 64 + n]);
    }
  } else {
    for (int idx = t; idx < 32 * 576; idx += 256) {
      int n = idx & 31, kk = idx >> 5;
      Wtcnt[n * 576 + kk] = (n < 25) ? f2b(cntw[kk * 25 + n]) : (unsigned short)0;
    }
  }
}

// ---------------------------------------------------------------------------
// K1: gate = sigmoid(coarse . gate_w + gate_b)  per coarse pixel
__global__ __launch_bounds__(256) void gate_kernel(
    const float* __restrict__ coarse, const float* __restrict__ gw,
    const float* __restrict__ gb, float* __restrict__ gatec) {
  int px   = blockIdx.x * 4 + (threadIdx.x >> 6);
  int lane = threadIdx.x & 63;
  const float4 a = *(const float4*)(coarse + (size_t)px * 256 + lane * 4);
  const float4 w = *(const float4*)(gw + lane * 4);
  float v = a.x * w.x + a.y * w.y + a.z * w.z + a.w * w.w;
  #pragma unroll
  for (int off = 32; off; off >>= 1) v += __shfl_xor(v, off);
  if (lane == 0) gatec[px] = 1.f / (1.f + expf(-(v + gb[0])));
}

// ---------------------------------------------------------------------------
// K2/K3: 1x1 conv embedding via MFMA: out_bf16[px][64] = in[px][K] @ Wt[64][K]
template <int K>
__global__ __launch_bounds__(256) void emb_mfma_kernel(
    const float* __restrict__ in, const unsigned short* __restrict__ Wt,
    const float* __restrict__ bias, unsigned short* __restrict__ out) {
  constexpr int LDA = K + 8;
  __shared__ __align__(16) unsigned short a_s[64 * LDA];
  int t = threadIdx.x;
  int pxb = blockIdx.x * 64;

  constexpr int KC = K / 4;
  for (int idx = t; idx < 64 * KC; idx += 256) {
    int px = idx / KC, kc = idx % KC;
    float4 v = *(const float4*)&in[(size_t)(pxb + px) * K + kc * 4];
    *(short4*)&a_s[px * LDA + kc * 4] =
        make_short4((short)f2b(v.x), (short)f2b(v.y), (short)f2b(v.z), (short)f2b(v.w));
  }
  __syncthreads();

  int wid = t >> 6, lane = t & 63;
  int lr = lane & 15, lg = lane >> 4;
  const f32x4 zero4 = {0.f, 0.f, 0.f, 0.f};
  f32x4 acc[4] = {zero4, zero4, zero4, zero4};

  #pragma unroll
  for (int kt = 0; kt < K / 32; kt++) {
    bf16x8 a = *(const bf16x8*)&a_s[(wid * 16 + lr) * LDA + kt * 32 + lg * 8];
    #pragma unroll
    for (int nt = 0; nt < 4; nt++) {
      bf16x8 bb = *(const bf16x8*)&Wt[(size_t)(nt * 16 + lr) * K + kt * 32 + lg * 8];
      acc[nt] = __builtin_amdgcn_mfma_f32_16x16x32_bf16(a, bb, acc[nt], 0, 0, 0);
    }
  }

  #pragma unroll
  for (int nt = 0; nt < 4; nt++) {
    int n = nt * 16 + lr;
    float bv = bias ? bias[n] : 0.f;
    #pragma unroll
    for (int r = 0; r < 4; r++) {
      int px = wid * 16 + lg * 4 + r;
      out[(size_t)(pxb + px) * 64 + n] = f2b(acc[nt][r] + bv);
    }
  }
}

// ---------------------------------------------------------------------------
// K4/K5: 3x3 content conv 64->25 via implicit-GEMM MFMA.
__global__ __launch_bounds__(256) void content_mfma_kernel(
    const unsigned short* __restrict__ emb, const unsigned short* __restrict__ Wtcnt,
    const float* __restrict__ cb, float* __restrict__ out, int Hd, int Wd) {
  constexpr int LDC = 72;
  __shared__ __align__(16) unsigned short a_s[100 * LDC];
  int t = threadIdx.x;
  int b = blockIdx.z;
  int i0 = blockIdx.y * 8, j0 = blockIdx.x * 8;

  for (int idx = t; idx < 100 * 16; idx += 256) {
    int cell = idx >> 4, ck = idx & 15;
    int gi = i0 - 1 + cell / 10;
    int gj = j0 - 1 + cell % 10;
    short4 v = make_short4(0, 0, 0, 0);
    if (gi >= 0 && gi < Hd && gj >= 0 && gj < Wd)
      v = *(const short4*)&emb[(size_t)((b * Hd + gi) * Wd + gj) * 64 + ck * 4];
    *(short4*)&a_s[cell * LDC + ck * 4] = v;
  }
  __syncthreads();

  int wid = t >> 6, lane = t & 63;
  int lr = lane & 15, lg = lane >> 4;
  int px = wid * 16 + lr;
  int pi = px >> 3, pj = px & 7;
  const f32x4 zero4 = {0.f, 0.f, 0.f, 0.f};
  f32x4 acc[2] = {zero4, zero4};

  #pragma unroll
  for (int di = 0; di < 3; di++) {
    #pragma unroll
    for (int dj = 0; dj < 3; dj++) {
      int cell = (pi + di) * 10 + (pj + dj);
      int tap = di * 3 + dj;
      #pragma unroll
      for (int kt = 0; kt < 2; kt++) {
        bf16x8 a = *(const bf16x8*)&a_s[cell * LDC + kt * 32 + lg * 8];
        #pragma unroll
        for (int nt = 0; nt < 2; nt++) {
          bf16x8 bb = *(const bf16x8*)&Wtcnt[(size_t)(nt * 16 + lr) * 576 + tap * 64 + kt * 32 + lg * 8];
          acc[nt] = __builtin_amdgcn_mfma_f32_16x16x32_bf16(a, bb, acc[nt], 0, 0, 0);
        }
      }
    }
  }

  #pragma unroll
  for (int nt = 0; nt < 2; nt++) {
    int ch = nt * 16 + lr;
    if (ch < 25) {
      float bv = cb[ch];
      #pragma unroll
      for (int r = 0; r < 4; r++) {
        int opx = wid * 16 + lg * 4 + r;
        int gi = i0 + (opx >> 3), gj = j0 + (opx & 7);
        out[(size_t)((b * Hd + gi) * Wd + gj) * 25 + ch] = acc[nt][r] + bv;
      }
    }
  }
}

// ---------------------------------------------------------------------------
// K6a: carafe only -> cu_g bf16 [Nf][256]
__global__ __launch_bounds__(256) void carafe_kernel(
    const float* __restrict__ coarse, const float* __restrict__ kff,
    const float* __restrict__ kfc, unsigned short* __restrict__ cu_g) {
  __shared__ __align__(16) unsigned short buf[256 * 72];
  __shared__ __align__(16) unsigned short m_ext[32 * 72];
  unsigned short* win_t = buf;
  unsigned short* cu_s  = buf;

  int t = threadIdx.x;
  int b = blockIdx.z;
  int i0 = blockIdx.y * 4, j0 = blockIdx.x * 8;
  int hw0 = (i0 >> 1) - 2, ww0 = (j0 >> 1) - 2;

  {
    #pragma unroll
    for (int p0 = 0; p0 < 48; p0 += 4) {
      unsigned short vals[4];
      #pragma unroll
      for (int q = 0; q < 4; q++) {
        int p = p0 + q;
        int h = hw0 + (p >> 3), w = ww0 + (p & 7);
        float v = 0.f;
        if (h >= 0 && h < 64 && w >= 0 && w < 64)
          v = coarse[(size_t)((b * 64 + h) * 64 + w) * 256 + t];
        vals[q] = f2b(v);
      }
      *(short4*)&win_t[t * 72 + p0] =
          make_short4((short)vals[0], (short)vals[1], (short)vals[2], (short)vals[3]);
    }
    short4 z4 = make_short4(0, 0, 0, 0);
    *(short4*)&win_t[t * 72 + 48] = z4;
    *(short4*)&win_t[t * 72 + 52] = z4;
    *(short4*)&win_t[t * 72 + 56] = z4;
    *(short4*)&win_t[t * 72 + 60] = z4;
  }
  if (t < 32) {
    int i = i0 + (t >> 3), j = j0 + (t & 7);
    size_t fpx = (size_t)((b * 128 + i) * 128 + j);
    size_t cpx = (size_t)((b * 64 + (i >> 1)) * 64 + (j >> 1));
    float v[25];
    float mx = -1e30f;
    #pragma unroll
    for (int m = 0; m < 25; m++) {
      v[m] = kff[fpx * 25 + m] + kfc[cpx * 25 + m];
      mx = fmaxf(mx, v[m]);
    }
    float s = 0.f;
    #pragma unroll
    for (int m = 0; m < 25; m++) { v[m] = expf(v[m] - mx); s += v[m]; }
    float inv = 1.f / s;
    unsigned* row32 = (unsigned*)&m_ext[t * 72];
    #pragma unroll
    for (int q = 0; q < 36; q++) row32[q] = 0;
    int wib = (t >> 3) >> 1, wjb = (t & 7) >> 1;
    #pragma unroll
    for (int di = 0; di < 5; di++)
      #pragma unroll
      for (int dj = 0; dj < 5; dj++)
        m_ext[t * 72 + (wib + di) * 8 + (wjb + dj)] = f2b(v[di * 5 + dj] * inv);
  }
  __syncthreads();

  int wid = t >> 6, lane = t & 63;
  int lr = lane & 15, lg = lane >> 4;
  const f32x4 zero4 = {0.f, 0.f, 0.f, 0.f};

  f32x4 acc0[2][4];
  #pragma unroll
  for (int mi = 0; mi < 2; mi++)
    #pragma unroll
    for (int ni = 0; ni < 4; ni++) acc0[mi][ni] = zero4;
  #pragma unroll
  for (int kt = 0; kt < 2; kt++) {
    bf16x8 a0 = *(const bf16x8*)&m_ext[lr * 72 + kt * 32 + lg * 8];
    bf16x8 a1 = *(const bf16x8*)&m_ext[(16 + lr) * 72 + kt * 32 + lg * 8];
    #pragma unroll
    for (int ni = 0; ni < 4; ni++) {
      bf16x8 bb = *(const bf16x8*)&win_t[(size_t)(wid * 64 + ni * 16 + lr) * 72 + kt * 32 + lg * 8];
      acc0[0][ni] = __builtin_amdgcn_mfma_f32_16x16x32_bf16(a0, bb, acc0[0][ni], 0, 0, 0);
      acc0[1][ni] = __builtin_amdgcn_mfma_f32_16x16x32_bf16(a1, bb, acc0[1][ni], 0, 0, 0);
    }
  }
  __syncthreads();  // win_t reads done; buf becomes cu_s

  #pragma unroll
  for (int mi = 0; mi < 2; mi++)
    #pragma unroll
    for (int ni = 0; ni < 4; ni++)
      #pragma unroll
      for (int r = 0; r < 4; r++)
        cu_s[(mi * 16 + lg * 4 + r) * 264 + wid * 64 + ni * 16 + lr] = f2b(acc0[mi][ni][r]);
  __syncthreads();

  // coalesced copy LDS -> global (32 px x 256 ch bf16)
  for (int c = t; c < 1024; c += 256) {
    int p = c >> 5, off = (c & 31) << 3;
    int gi = i0 + (p >> 3), gj = j0 + (p & 7);
    bf16x8 v = *(const bf16x8*)&cu_s[p * 264 + off];
    *(bf16x8*)&cu_g[(size_t)((b * 128 + gi) * 128 + gj) * 256 + off] = v;
  }
}

// ---------------------------------------------------------------------------
// K6b: chained projections + gated mix. M=64 rows per block (1024 blocks).
// LDS A-tile 33.8 KB -> 4 blocks/CU; VGPR capped via launch_bounds(256,4).
__global__ __launch_bounds__(256, 4) void proj_kernel(
    const unsigned short* __restrict__ cu_g, const float* __restrict__ gatec,
    const unsigned short* __restrict__ Wt1, const float* __restrict__ b1,
    const unsigned short* __restrict__ Wt2, const float* __restrict__ b2,
    float* __restrict__ out) {
  __shared__ __align__(16) unsigned short a_s[64 * 264];  // 33792 B, reused for c_out
  __shared__ float g_s[32];
  int t = threadIdx.x;
  size_t m0 = (size_t)blockIdx.x * 64;
  int b_  = blockIdx.x >> 8;          // batch (256 blocks per batch)
  int ii  = (blockIdx.x >> 1) & 127;  // fine row i
  int j0h = (blockIdx.x & 1) * 32;    // j0>>1

  for (int c = t; c < 2048; c += 256) {
    int row = c >> 5, off = (c & 31) << 3;
    *(bf16x8*)&a_s[row * 264 + off] = *(const bf16x8*)&cu_g[(m0 + row) * 256 + off];
  }
  if (t < 32) g_s[t] = gatec[(size_t)(b_ * 64 + (ii >> 1)) * 64 + j0h + t];
  __syncthreads();

  int wid = t >> 6, lane = t & 63;
  int lr = lane & 15, lg = lane >> 4;
  const f32x4 zero4 = {0.f, 0.f, 0.f, 0.f};
  f32x4 acc[4][4];

  // ---- GEMM1: c_out = cu @ W1 + b1 ----
  #pragma unroll
  for (int mt = 0; mt < 4; mt++)
    #pragma unroll
    for (int ni = 0; ni < 4; ni++) acc[mt][ni] = zero4;
  #pragma unroll 2
  for (int kt = 0; kt < 8; kt++) {
    bf16x8 a[4];
    #pragma unroll
    for (int mt = 0; mt < 4; mt++)
      a[mt] = *(const bf16x8*)&a_s[(mt * 16 + lr) * 264 + kt * 32 + lg * 8];
    #pragma unroll
    for (int ni = 0; ni < 4; ni++) {
      bf16x8 bb = *(const bf16x8*)&Wt1[(size_t)(wid * 64 + ni * 16 + lr) * 256 + kt * 32 + lg * 8];
      #pragma unroll
      for (int mt = 0; mt < 4; mt++)
        acc[mt][ni] = __builtin_amdgcn_mfma_f32_16x16x32_bf16(a[mt], bb, acc[mt][ni], 0, 0, 0);
    }
  }
  float b1v[4];
  #pragma unroll
  for (int ni = 0; ni < 4; ni++) b1v[ni] = b1[wid * 64 + ni * 16 + lr];
  __syncthreads();  // all GEMM1 reads done

  #pragma unroll
  for (int mt = 0; mt < 4; mt++)
    #pragma unroll
    for (int ni = 0; ni < 4; ni++)
      #pragma unroll
      for (int r = 0; r < 4; r++)
        a_s[(mt * 16 + lg * 4 + r) * 264 + wid * 64 + ni * 16 + lr] =
            f2b(acc[mt][ni][r] + b1v[ni]);
  __syncthreads();

  // ---- GEMM2: f_out = c_out @ W2 + b2 (reuse acc registers) ----
  #pragma unroll
  for (int mt = 0; mt < 4; mt++)
    #pragma unroll
    for (int ni = 0; ni < 4; ni++) acc[mt][ni] = zero4;
  #pragma unroll 2
  for (int kt = 0; kt < 8; kt++) {
    bf16x8 a[4];
    #pragma unroll
    for (int mt = 0; mt < 4; mt++)
      a[mt] = *(const bf16x8*)&a_s[(mt * 16 + lr) * 264 + kt * 32 + lg * 8];
    #pragma unroll
    for (int ni = 0; ni < 4; ni++) {
      bf16x8 bb = *(const bf16x8*)&Wt2[(size_t)(wid * 64 + ni * 16 + lr) * 256 + kt * 32 + lg * 8];
      #pragma unroll
      for (int mt = 0; mt < 4; mt++)
        acc[mt][ni] = __builtin_amdgcn_mfma_f32_16x16x32_bf16(a[mt], bb, acc[mt][ni], 0, 0, 0);
    }
  }
  float b2v[4];
  #pragma unroll
  for (int ni = 0; ni < 4; ni++) b2v[ni] = b2[wid * 64 + ni * 16 + lr];

  // ---- mix + store ----
  #pragma unroll
  for (int mt = 0; mt < 4; mt++) {
    #pragma unroll
    for (int r = 0; r < 4; r++) {
      int row = mt * 16 + lg * 4 + r;
      float g = g_s[row >> 1];
      size_t obase = (m0 + row) * 256;
      #pragma unroll
      for (int ni = 0; ni < 4; ni++) {
        int col = wid * 64 + ni * 16 + lr;
        float f_out = acc[mt][ni][r] + b2v[ni];
        float c_outv = b2f(a_s[row * 264 + col]);
        out[obase + col] = g * f_out + (1.f - g) * c_outv;
      }
    }
  }
}

// ---------------------------------------------------------------------------
// Fallback: R2's fully-fused kernel (used only if ws is too small for cu_g)
__global__ __launch_bounds__(256) void fuse_mfma_kernel(
    const float* __restrict__ coarse, const float* __restrict__ kff,
    const float* __restrict__ kfc, const float* __restrict__ gatec,
    const unsigned short* __restrict__ Wt1, const float* __restrict__ b1,
    const unsigned short* __restrict__ Wt2, const float* __restrict__ b2,
    float* __restrict__ out) {
  __shared__ __align__(16) unsigned short buf[256 * 72];
  __shared__ __align__(16) unsigned short m_ext[32 * 72];
  __shared__ float g_s[32];
  unsigned short* win_t = buf;
  unsigned short* cu_s  = buf;

  int t = threadIdx.x;
  int b = blockIdx.z;
  int i0 = blockIdx.y * 4, j0 = blockIdx.x * 8;
  int hw0 = (i0 >> 1) - 2, ww0 = (j0 >> 1) - 2;

  {
    #pragma unroll
    for (int p0 = 0; p0 < 48; p0 += 4) {
      unsigned short vals[4];
      #pragma unroll
      for (int q = 0; q < 4; q++) {
        int p = p0 + q;
        int h = hw0 + (p >> 3), w = ww0 + (p & 7);
        float v = 0.f;
        if (h >= 0 && h < 64 && w >= 0 && w < 64)
          v = coarse[(size_t)((b * 64 + h) * 64 + w) * 256 + t];
        vals[q] = f2b(v);
      }
      *(short4*)&win_t[t * 72 + p0] =
          make_short4((short)vals[0], (short)vals[1], (short)vals[2], (short)vals[3]);
    }
    short4 z4 = make_short4(0, 0, 0, 0);
    *(short4*)&win_t[t * 72 + 48] = z4;
    *(short4*)&win_t[t * 72 + 52] = z4;
    *(short4*)&win_t[t * 72 + 56] = z4;
    *(short4*)&win_t[t * 72 + 60] = z4;
  }
  if (t < 32) {
    int i = i0 + (t >> 3), j = j0 + (t & 7);
    size_t fpx = (size_t)((b * 128 + i) * 128 + j);
    size_t cpx = (size_t)((b * 64 + (i >> 1)) * 64 + (j >> 1));
    float v[25];
    float mx = -1e30f;
    #pragma unroll
    for (int m = 0; m < 25; m++) {
      v[m] = kff[fpx * 25 + m] + kfc[cpx * 25 + m];
      mx = fmaxf(mx, v[m]);
    }
    float s = 0.f;
    #pragma unroll
    for (int m = 0; m < 25; m++) { v[m] = expf(v[m] - mx); s += v[m]; }
    float inv = 1.f / s;
    unsigned* row32 = (unsigned*)&m_ext[t * 72];
    #pragma unroll
    for (int q = 0; q < 36; q++) row32[q] = 0;
    int wib = (t >> 3) >> 1, wjb = (t & 7) >> 1;
    #pragma unroll
    for (int di = 0; di < 5; di++)
      #pragma unroll
      for (int dj = 0; dj < 5; dj++)
        m_ext[t * 72 + (wib + di) * 8 + (wjb + dj)] = f2b(v[di * 5 + dj] * inv);
    g_s[t] = gatec[cpx];
  }
  __syncthreads();

  int wid = t >> 6, lane = t & 63;
  int lr = lane & 15, lg = lane >> 4;
  const f32x4 zero4 = {0.f, 0.f, 0.f, 0.f};

  f32x4 acc0[2][4];
  #pragma unroll
  for (int mi = 0; mi < 2; mi++)
    #pragma unroll
    for (int ni = 0; ni < 4; ni++) acc0[mi][ni] = zero4;
  #pragma unroll
  for (int kt = 0; kt < 2; kt++) {
    bf16x8 a0 = *(const bf16x8*)&m_ext[lr * 72 + kt * 32 + lg * 8];
    bf16x8 a1 = *(const bf16x8*)&m_ext[(16 + lr) * 72 + kt * 32 + lg * 8];
    #pragma unroll
    for (int ni = 0; ni < 4; ni++) {
      bf16x8 bb = *(const bf16x8*)&win_t[(size_t)(wid * 64 + ni * 16 + lr) * 72 + kt * 32 + lg * 8];
      acc0[0][ni] = __builtin_amdgcn_mfma_f32_16x16x32_bf16(a0, bb, acc0[0][ni], 0, 0, 0);
      acc0[1][ni] = __builtin_amdgcn_mfma_f32_16x16x32_bf16(a1, bb, acc0[1][ni], 0, 0, 0);
    }
  }
  __syncthreads();

  #pragma unroll
  for (int mi = 0; mi < 2; mi++)
    #pragma unroll
    for (int ni = 0; ni < 4; ni++)
      #pragma unroll
      for (int r = 0; r < 4; r++)
        cu_s[(mi * 16 + lg * 4 + r) * 264 + wid * 64 + ni * 16 + lr] = f2b(acc0[mi][ni][r]);
  __syncthreads();

  f32x4 acc1[2][4];
  #pragma unroll
  for (int mi = 0; mi < 2; mi++)
    #pragma unroll
    for (int ni = 0; ni < 4; ni++) acc1[mi][ni] = zero4;
  #pragma unroll 2
  for (int kt = 0; kt < 8; kt++) {
    bf16x8 a0 = *(const bf16x8*)&cu_s[lr * 264 + kt * 32 + lg * 8];
    bf16x8 a1 = *(const bf16x8*)&cu_s[(16 + lr) * 264 + kt * 32 + lg * 8];
    #pragma unroll
    for (int ni = 0; ni < 4; ni++) {
      bf16x8 bb = *(const bf16x8*)&Wt1[(size_t)(wid * 64 + ni * 16 + lr) * 256 + kt * 32 + lg * 8];
      acc1[0][ni] = __builtin_amdgcn_mfma_f32_16x16x32_bf16(a0, bb, acc1[0][ni], 0, 0, 0);
      acc1[1][ni] = __builtin_amdgcn_mfma_f32_16x16x32_bf16(a1, bb, acc1[1][ni], 0, 0, 0);
    }
  }
  float b1v[4];
  #pragma unroll
  for (int ni = 0; ni < 4; ni++) b1v[ni] = b1[wid * 64 + ni * 16 + lr];
  __syncthreads();

  #pragma unroll
  for (int mi = 0; mi < 2; mi++)
    #pragma unroll
    for (int ni = 0; ni < 4; ni++)
      #pragma unroll
      for (int r = 0; r < 4; r++)
        cu_s[(mi * 16 + lg * 4 + r) * 264 + wid * 64 + ni * 16 + lr] =
            f2b(acc1[mi][ni][r] + b1v[ni]);
  __syncthreads();

  f32x4 acc2[2][4];
  #pragma unroll
  for (int mi = 0; mi < 2; mi++)
    #pragma unroll
    for (int ni = 0; ni < 4; ni++) acc2[mi][ni] = zero4;
  #pragma unroll 2
  for (int kt = 0; kt < 8; kt++) {
    bf16x8 a0 = *(const bf16x8*)&cu_s[lr * 264 + kt * 32 + lg * 8];
    bf16x8 a1 = *(const bf16x8*)&cu_s[(16 + lr) * 264 + kt * 32 + lg * 8];
    #pragma unroll
    for (int ni = 0; ni < 4; ni++) {
      bf16x8 bb = *(const bf16x8*)&Wt2[(size_t)(wid * 64 + ni * 16 + lr) * 256 + kt * 32 + lg * 8];
      acc2[0][ni] = __builtin_amdgcn_mfma_f32_16x16x32_bf16(a0, bb, acc2[0][ni], 0, 0, 0);
      acc2[1][ni] = __builtin_amdgcn_mfma_f32_16x16x32_bf16(a1, bb, acc2[1][ni], 0, 0, 0);
    }
  }
  float b2v[4];
  #pragma unroll
  for (int ni = 0; ni < 4; ni++) b2v[ni] = b2[wid * 64 + ni * 16 + lr];

  #pragma unroll
  for (int mi = 0; mi < 2; mi++)
    #pragma unroll
    for (int ni = 0; ni < 4; ni++)
      #pragma unroll
      for (int r = 0; r < 4; r++) {
        int px = mi * 16 + lg * 4 + r;
        float g = g_s[px];
        int i = i0 + (px >> 3), j = j0 + (px & 7);
        float c_out = acc1[mi][ni][r] + b1v[ni];
        float f_out = acc2[mi][ni][r] + b2v[ni];
        out[(size_t)((b * 128 + i) * 128 + j) * 256 + wid * 64 + ni * 16 + lr] =
            g * f_out + (1.f - g) * c_out;
      }
}

// ---------------------------------------------------------------------------
extern "C" void kernel_launch(void* const* d_in, const int* in_sizes, int n_in,
                              void* d_out, int out_size, void* d_ws, size_t ws_size,
                              hipStream_t stream) {
  const float* fine        = (const float*)d_in[0];
  const float* coarse      = (const float*)d_in[1];
  const float* gate_w      = (const float*)d_in[2];
  const float* gate_b      = (const float*)d_in[3];
  const float* ss_fine_w   = (const float*)d_in[4];
  const float* ss_fine_b   = (const float*)d_in[5];
  const float* ss_coarse_w = (const float*)d_in[6];
  const float* ss_content_w= (const float*)d_in[7];
  const float* ss_content_b= (const float*)d_in[8];
  const float* W1          = (const float*)d_in[9];
  const float* b1          = (const float*)d_in[10];
  const float* W2          = (const float*)d_in[11];
  const float* b2          = (const float*)d_in[12];
  float* out = (float*)d_out;

  char* ws = (char*)d_ws;
  size_t off = 0;
  float* gatec = (float*)(ws + off); off += 131072;
  unsigned short* femb = (unsigned short*)(ws + off); off += (size_t)Nf * 64 * 2;
  unsigned short* cemb = (unsigned short*)(ws + off); off += (size_t)Nc * 64 * 2;
  float* kff   = (float*)(ws + off); off += (size_t)Nf * 25 * 4;
  float* kfc   = (float*)(ws + off); off += (size_t)Nc * 25 * 4;
  unsigned short* Wt1 = (unsigned short*)(ws + off); off += 65536 * 2;
  unsigned short* Wt2 = (unsigned short*)(ws + off); off += 65536 * 2;
  unsigned short* Wtf = (unsigned short*)(ws + off); off += 64 * 128 * 2;
  unsigned short* Wtc = (unsigned short*)(ws + off); off += 64 * 256 * 2;
  unsigned short* Wtcnt = (unsigned short*)(ws + off); off += 32 * 576 * 2;
  unsigned short* cu_g = (unsigned short*)(ws + off); off += (size_t)Nf * 256 * 2;
  bool split = (ws_size >= off);

  wprep_kernel<<<dim3(4, 4, 2), 256, 0, stream>>>(W1, W2, Wt1, Wt2);
  sprep_kernel<<<3, 256, 0, stream>>>(ss_fine_w, ss_coarse_w, ss_content_w, Wtf, Wtc, Wtcnt);
  gate_kernel<<<Nc / 4, 256, 0, stream>>>(coarse, gate_w, gate_b, gatec);
  emb_mfma_kernel<128><<<Nf / 64, 256, 0, stream>>>(fine, Wtf, ss_fine_b, femb);
  emb_mfma_kernel<256><<<Nc / 64, 256, 0, stream>>>(coarse, Wtc, nullptr, cemb);
  content_mfma_kernel<<<dim3(Wf / 8, Hf / 8, Bb), 256, 0, stream>>>(femb, Wtcnt, ss_content_b, kff, Hf, Wf);
  content_mfma_kernel<<<dim3(Wc / 8, Hc / 8, Bb), 256, 0, stream>>>(cemb, Wtcnt, ss_content_b, kfc, Hc, Wc);
  if (split) {
    carafe_kernel<<<dim3(Wf / 8, Hf / 4, Bb), 256, 0, stream>>>(coarse, kff, kfc, cu_g);
    proj_kernel<<<Nf / 64, 256, 0, stream>>>(cu_g, gatec, Wt1, b1, Wt2, b2, out);
  } else {
    fuse_mfma_kernel<<<dim3(Wf / 8, Hf / 4, Bb), 256, 0, stream>>>(
        coarse, kff, kfc, gatec, Wt1, b1, Wt2, b2, out);
  }
}